// Round 1
// baseline (1076.232 us; speedup 1.0000x reference)
//
#include <hip/hip_runtime.h>
#include <math.h>

#define H 128
#define LN_EPS 1e-5f

__device__ __forceinline__ int imin(int a, int b) { return a < b ? a : b; }
__device__ __forceinline__ int clampi(int v, int lo, int hi) { return v < lo ? lo : (v > hi ? hi : v); }

// ---------------- CSR build ----------------
__global__ void count_kernel(const int* __restrict__ dst, int* __restrict__ cnt, int E, int n) {
    int e = blockIdx.x * blockDim.x + threadIdx.x;
    if (e < E) {
        int d = clampi(dst[e], 0, n - 1);
        atomicAdd(&cnt[d], 1);
    }
}

__global__ void scan_kernel(const int* __restrict__ cnt, int* __restrict__ cursor, int n) {
    __shared__ int sh[1024];
    const int tid = threadIdx.x;
    const int per = (n + 1023) >> 10;
    const int b = tid * per;
    int s = 0;
    for (int i = 0; i < per; ++i) { int idx = b + i; if (idx < n) s += cnt[idx]; }
    sh[tid] = s;
    __syncthreads();
    for (int off = 1; off < 1024; off <<= 1) {
        int u = (tid >= off) ? sh[tid - off] : 0;
        __syncthreads();
        if (tid >= off) sh[tid] += u;
        __syncthreads();
    }
    int run = sh[tid] - s;  // exclusive prefix for this thread's chunk
    for (int i = 0; i < per; ++i) {
        int idx = b + i;
        if (idx < n) { cursor[idx] = run; run += cnt[idx]; }
    }
}

__global__ void bucket_kernel(const int* __restrict__ src, const int* __restrict__ dst,
                              const float* __restrict__ ew, int* __restrict__ cursor,
                              int* __restrict__ srcS, int* __restrict__ dstS,
                              float* __restrict__ wS, int E, int n) {
    int e = blockIdx.x * blockDim.x + threadIdx.x;
    if (e < E) {
        int d = clampi(dst[e], 0, n - 1);
        int s = clampi(src[e], 0, n - 1);
        int p = atomicAdd(&cursor[d], 1);
        srcS[p] = s; dstS[p] = d; wS[p] = ew[e];
    }
}

// ---------------- per-node dst-half precompute: tdst = x @ W_bot + msg_b ----------------
__global__ __launch_bounds__(256) void pre_tdst_kernel(
    const float* __restrict__ x, const float* __restrict__ wbot,
    const float* __restrict__ bias, float* __restrict__ tdst, int n)
{
    __shared__ float Ws[128 * 128];
    __shared__ float xs[64 * 132];
    const int tid = threadIdx.x;
    const int r0 = blockIdx.x * 64;
    {
        const float4* wg = (const float4*)wbot;
        float4* wl = (float4*)Ws;
        for (int i = tid; i < 4096; i += 256) wl[i] = wg[i];
    }
    {
        int r = tid >> 2;
        int rr = imin(r0 + r, n - 1);
        int c0 = (tid & 3) * 32;
        const float4* xr = (const float4*)(x + (size_t)rr * H + c0);
        float4* dp = (float4*)&xs[r * 132 + c0];
        #pragma unroll
        for (int i = 0; i < 8; ++i) dp[i] = xr[i];
    }
    __syncthreads();
    float acc[8][4];
    #pragma unroll
    for (int i = 0; i < 8; ++i) { acc[i][0] = 0.f; acc[i][1] = 0.f; acc[i][2] = 0.f; acc[i][3] = 0.f; }
    const int eg = (tid >> 5) * 8;
    const int dg = (tid & 31) * 4;
    #pragma unroll 4
    for (int k = 0; k < 128; ++k) {
        float4 wv = *(const float4*)&Ws[k * 128 + dg];
        #pragma unroll
        for (int i = 0; i < 8; ++i) {
            float xv = xs[(eg + i) * 132 + k];
            acc[i][0] = fmaf(xv, wv.x, acc[i][0]);
            acc[i][1] = fmaf(xv, wv.y, acc[i][1]);
            acc[i][2] = fmaf(xv, wv.z, acc[i][2]);
            acc[i][3] = fmaf(xv, wv.w, acc[i][3]);
        }
    }
    float4 bb = *(const float4*)(bias + dg);
    #pragma unroll
    for (int i = 0; i < 8; ++i) {
        int row = r0 + eg + i;
        if (row < n) {
            float4 o;
            o.x = acc[i][0] + bb.x; o.y = acc[i][1] + bb.y;
            o.z = acc[i][2] + bb.z; o.w = acc[i][3] + bb.w;
            *(float4*)&tdst[(size_t)row * H + dg] = o;
        }
    }
}

// ---------------- per-edge: msg = relu(LN(x[src]@W_top + tdst[dst])) * w  → segmented scatter ----------------
__global__ __launch_bounds__(256) void edge_msg_kernel(
    const float* __restrict__ x, const int* __restrict__ srcS,
    const int* __restrict__ dstS, const float* __restrict__ wS,
    const float* __restrict__ wtop, const float* __restrict__ tdst,
    const float* __restrict__ gamma, const float* __restrict__ beta,
    float* __restrict__ msgs, int E)
{
    __shared__ float Ws[128 * 128];
    __shared__ float xs[64 * 132];     // GEMM layout; reused as t[64][129] after GEMM
    __shared__ float mu_s[64], ri_s[64], w_s[64];
    __shared__ int dst_s[64], src_s[64];

    const int tid = threadIdx.x;
    const int e0 = blockIdx.x * 64;

    {
        const float4* wg = (const float4*)wtop;
        float4* wl = (float4*)Ws;
        for (int i = tid; i < 4096; i += 256) wl[i] = wg[i];
    }
    if (tid < 64) {
        int e = e0 + tid;
        if (e < E) { src_s[tid] = srcS[e]; dst_s[tid] = dstS[e]; w_s[tid] = wS[e]; }
        else       { src_s[tid] = 0;       dst_s[tid] = -1;      w_s[tid] = 0.f; }
    }
    __syncthreads();
    {
        int r = tid >> 2;
        int c0 = (tid & 3) * 32;
        const float4* xr = (const float4*)(x + (size_t)src_s[r] * H + c0);
        float4* dp = (float4*)&xs[r * 132 + c0];
        #pragma unroll
        for (int i = 0; i < 8; ++i) dp[i] = xr[i];
    }
    __syncthreads();

    float acc[8][4];
    #pragma unroll
    for (int i = 0; i < 8; ++i) { acc[i][0] = 0.f; acc[i][1] = 0.f; acc[i][2] = 0.f; acc[i][3] = 0.f; }
    const int eg = (tid >> 5) * 8;
    const int dg = (tid & 31) * 4;
    #pragma unroll 4
    for (int k = 0; k < 128; ++k) {
        float4 wv = *(const float4*)&Ws[k * 128 + dg];
        #pragma unroll
        for (int i = 0; i < 8; ++i) {
            float xv = xs[(eg + i) * 132 + k];
            acc[i][0] = fmaf(xv, wv.x, acc[i][0]);
            acc[i][1] = fmaf(xv, wv.y, acc[i][1]);
            acc[i][2] = fmaf(xv, wv.z, acc[i][2]);
            acc[i][3] = fmaf(xv, wv.w, acc[i][3]);
        }
    }
    __syncthreads();
    // write t into xs overlay with stride 129 (all indices disjoint)
    #pragma unroll
    for (int i = 0; i < 8; ++i) {
        xs[(eg + i) * 129 + dg + 0] = acc[i][0];
        xs[(eg + i) * 129 + dg + 1] = acc[i][1];
        xs[(eg + i) * 129 + dg + 2] = acc[i][2];
        xs[(eg + i) * 129 + dg + 3] = acc[i][3];
    }
    __syncthreads();
    // LN stats: 4 threads per edge, add tdst[dst] in the same pass
    {
        int e = tid >> 2;
        int q = tid & 3;
        int d0 = q * 32;
        int dn = dst_s[e];
        const float* td = tdst + (size_t)(dn < 0 ? 0 : dn) * H + d0;
        float s = 0.f, s2 = 0.f;
        #pragma unroll 8
        for (int i = 0; i < 32; ++i) {
            float v = xs[e * 129 + d0 + i] + td[i];
            xs[e * 129 + d0 + i] = v;
            s += v;
            s2 = fmaf(v, v, s2);
        }
        s  += __shfl_xor(s, 1);  s  += __shfl_xor(s, 2);
        s2 += __shfl_xor(s2, 1); s2 += __shfl_xor(s2, 2);
        if (q == 0) {
            float mu = s * (1.f / 128.f);
            float var = s2 * (1.f / 128.f) - mu * mu;
            mu_s[e] = mu;
            ri_s[e] = rsqrtf(fmaxf(var, 0.f) + LN_EPS);
        }
    }
    __syncthreads();
    // segmented scatter: thread owns dim d, scans 32 sorted edges; 1 atomic per run
    {
        int d = tid & 127;
        int h = tid >> 7;
        float gd = gamma[d], bd = beta[d];
        int eS = h * 32;
        int prev = dst_s[eS];
        float sum = 0.f;
        for (int i = 0; i < 32; ++i) {
            int e = eS + i;
            int dn = dst_s[e];
            if (dn != prev) {
                if (prev >= 0) atomicAdd(&msgs[(size_t)prev * H + d], sum);
                sum = 0.f; prev = dn;
            }
            float v = (xs[e * 129 + d] - mu_s[e]) * ri_s[e];
            v = fmaf(v, gd, bd);
            v = fmaxf(v, 0.f) * w_s[e];
            sum += v;
        }
        if (prev >= 0) atomicAdd(&msgs[(size_t)prev * H + d], sum);
    }
}

// ---------------- update: out = gate*relu(LN(x@Wu_top + messages@Wu_bot + b)) + (1-gate)*x ----------------
__global__ __launch_bounds__(256) void update_kernel(
    const float* __restrict__ x, const float* __restrict__ msgs,
    const int* __restrict__ cnt, const float* __restrict__ upd_w,
    const float* __restrict__ upd_b, const float* __restrict__ g,
    const float* __restrict__ beta, const float* __restrict__ gate_w,
    const float* __restrict__ gate_b, float* __restrict__ out, int n)
{
    __shared__ float Ws[128 * 128];
    __shared__ float xs[64 * 132];   // x tile (persists)
    __shared__ float mt[64 * 132];   // messages tile, then t overlay stride 129
    __shared__ float gate_s[64], mu_s[64], ri_s[64];

    const int tid = threadIdx.x;
    const int r0 = blockIdx.x * 64;

    {
        int r = tid >> 2;
        int rr = imin(r0 + r, n - 1);
        int c0 = (tid & 3) * 32;
        const float4* xr = (const float4*)(x + (size_t)rr * H + c0);
        float4* dp = (float4*)&xs[r * 132 + c0];
        #pragma unroll
        for (int i = 0; i < 8; ++i) dp[i] = xr[i];
    }
    {
        const float4* wg = (const float4*)upd_w;  // rows 0..127 (x half)
        float4* wl = (float4*)Ws;
        for (int i = tid; i < 4096; i += 256) wl[i] = wg[i];
    }
    {
        int r = tid >> 2;
        int rr = imin(r0 + r, n - 1);
        int c0 = (tid & 3) * 32;
        float c = (float)cnt[rr];
        float scale = (c > 0.f) ? 1.f / (c + 1e-8f) : 0.f;
        const float4* mr = (const float4*)(msgs + (size_t)rr * H + c0);
        float4* dp = (float4*)&mt[r * 132 + c0];
        #pragma unroll
        for (int i = 0; i < 8; ++i) {
            float4 v = mr[i];
            v.x *= scale; v.y *= scale; v.z *= scale; v.w *= scale;
            dp[i] = v;
        }
    }
    __syncthreads();
    // gate = sigmoid(x . gate_w + gate_b)
    {
        int r = tid >> 2;
        int q = tid & 3;
        const float* gw = gate_w + q * 32;
        const float* xr = &xs[r * 132 + q * 32];
        float s = 0.f;
        #pragma unroll 8
        for (int i = 0; i < 32; ++i) s = fmaf(xr[i], gw[i], s);
        s += __shfl_xor(s, 1); s += __shfl_xor(s, 2);
        if (q == 0) gate_s[r] = 1.f / (1.f + expf(-(s + gate_b[0])));
    }

    float acc[8][4];
    #pragma unroll
    for (int i = 0; i < 8; ++i) { acc[i][0] = 0.f; acc[i][1] = 0.f; acc[i][2] = 0.f; acc[i][3] = 0.f; }
    const int eg = (tid >> 5) * 8;
    const int dg = (tid & 31) * 4;
    #pragma unroll 4
    for (int k = 0; k < 128; ++k) {           // phase 1: x @ Wu_top
        float4 wv = *(const float4*)&Ws[k * 128 + dg];
        #pragma unroll
        for (int i = 0; i < 8; ++i) {
            float xv = xs[(eg + i) * 132 + k];
            acc[i][0] = fmaf(xv, wv.x, acc[i][0]);
            acc[i][1] = fmaf(xv, wv.y, acc[i][1]);
            acc[i][2] = fmaf(xv, wv.z, acc[i][2]);
            acc[i][3] = fmaf(xv, wv.w, acc[i][3]);
        }
    }
    __syncthreads();
    {
        const float4* wg = (const float4*)(upd_w + 16384);  // rows 128..255 (msg half)
        float4* wl = (float4*)Ws;
        for (int i = tid; i < 4096; i += 256) wl[i] = wg[i];
    }
    __syncthreads();
    #pragma unroll 4
    for (int k = 0; k < 128; ++k) {           // phase 2: messages @ Wu_bot
        float4 wv = *(const float4*)&Ws[k * 128 + dg];
        #pragma unroll
        for (int i = 0; i < 8; ++i) {
            float xv = mt[(eg + i) * 132 + k];
            acc[i][0] = fmaf(xv, wv.x, acc[i][0]);
            acc[i][1] = fmaf(xv, wv.y, acc[i][1]);
            acc[i][2] = fmaf(xv, wv.z, acc[i][2]);
            acc[i][3] = fmaf(xv, wv.w, acc[i][3]);
        }
    }
    __syncthreads();
    float4 ub = *(const float4*)(upd_b + dg);
    #pragma unroll
    for (int i = 0; i < 8; ++i) {
        mt[(eg + i) * 129 + dg + 0] = acc[i][0] + ub.x;
        mt[(eg + i) * 129 + dg + 1] = acc[i][1] + ub.y;
        mt[(eg + i) * 129 + dg + 2] = acc[i][2] + ub.z;
        mt[(eg + i) * 129 + dg + 3] = acc[i][3] + ub.w;
    }
    __syncthreads();
    {
        int r = tid >> 2;
        int q = tid & 3;
        int d0 = q * 32;
        float s = 0.f, s2 = 0.f;
        #pragma unroll 8
        for (int i = 0; i < 32; ++i) {
            float v = mt[r * 129 + d0 + i];
            s += v;
            s2 = fmaf(v, v, s2);
        }
        s  += __shfl_xor(s, 1);  s  += __shfl_xor(s, 2);
        s2 += __shfl_xor(s2, 1); s2 += __shfl_xor(s2, 2);
        if (q == 0) {
            float mu = s * (1.f / 128.f);
            float var = s2 * (1.f / 128.f) - mu * mu;
            mu_s[r] = mu;
            ri_s[r] = rsqrtf(fmaxf(var, 0.f) + LN_EPS);
        }
    }
    __syncthreads();
    {
        int d = tid & 127;
        int h = tid >> 7;
        float gd = g[d], bd = beta[d];
        for (int i = 0; i < 32; ++i) {
            int r = h * 32 + i;
            int row = r0 + r;
            if (row < n) {
                float v = fmaf((mt[r * 129 + d] - mu_s[r]) * ri_s[r], gd, bd);
                v = fmaxf(v, 0.f);
                float gt = gate_s[r];
                float xv = xs[r * 132 + d];
                out[(size_t)row * H + d] = fmaf(gt, v - xv, xv);
            }
        }
    }
}

extern "C" void kernel_launch(void* const* d_in, const int* in_sizes, int n_in,
                              void* d_out, int out_size, void* d_ws, size_t ws_size,
                              hipStream_t stream)
{
    const float* x        = (const float*)d_in[0];
    const int*   ei       = (const int*)d_in[1];
    const float* ew       = (const float*)d_in[2];
    const float* msg_w    = (const float*)d_in[3];
    const float* msg_b    = (const float*)d_in[4];
    const float* msg_g    = (const float*)d_in[5];
    const float* msg_beta = (const float*)d_in[6];
    const float* upd_w    = (const float*)d_in[7];
    const float* upd_b    = (const float*)d_in[8];
    const float* upd_g    = (const float*)d_in[9];
    const float* upd_beta = (const float*)d_in[10];
    const float* gate_w   = (const float*)d_in[11];
    const float* gate_b   = (const float*)d_in[12];

    const int n = in_sizes[0] / H;
    const int E = in_sizes[2];
    const int* src = ei;
    const int* dst = ei + E;

    char* p = (char*)d_ws;
    auto alloc = [&](size_t bytes) { char* r = p; p += (bytes + 255) & ~(size_t)255; return r; };
    int*   cnt    = (int*)alloc((size_t)n * 4);
    int*   cursor = (int*)alloc((size_t)n * 4);
    int*   srcS   = (int*)alloc((size_t)E * 4);
    int*   dstS   = (int*)alloc((size_t)E * 4);
    float* wS     = (float*)alloc((size_t)E * 4);
    float* tdst   = (float*)alloc((size_t)n * H * 4);
    float* msgs   = (float*)alloc((size_t)n * H * 4);

    hipMemsetAsync(cnt, 0, (size_t)n * 4, stream);
    hipMemsetAsync(msgs, 0, (size_t)n * H * 4, stream);

    int eb = (E + 255) / 256;
    count_kernel<<<eb, 256, 0, stream>>>(dst, cnt, E, n);
    scan_kernel<<<1, 1024, 0, stream>>>(cnt, cursor, n);
    bucket_kernel<<<eb, 256, 0, stream>>>(src, dst, ew, cursor, srcS, dstS, wS, E, n);
    pre_tdst_kernel<<<(n + 63) / 64, 256, 0, stream>>>(x, msg_w + 128 * H, msg_b, tdst, n);
    edge_msg_kernel<<<(E + 63) / 64, 256, 0, stream>>>(x, srcS, dstS, wS, msg_w, tdst, msg_g, msg_beta, msgs, E);
    update_kernel<<<(n + 63) / 64, 256, 0, stream>>>(x, msgs, cnt, upd_w, upd_b, upd_g, upd_beta, gate_w, gate_b, (float*)d_out, n);
}

// Round 2
// 529.195 us; speedup vs baseline: 2.0337x; 2.0337x over previous
//
#include <hip/hip_runtime.h>
#include <math.h>

#define H 128
#define LN_EPS 1e-5f

typedef __attribute__((ext_vector_type(8))) short  bf16x8;
typedef __attribute__((ext_vector_type(4))) float  f32x4;
typedef __attribute__((ext_vector_type(8))) unsigned short ushort8v;

__device__ __forceinline__ int imin(int a, int b) { return a < b ? a : b; }
__device__ __forceinline__ int clampi(int v, int lo, int hi) { return v < lo ? lo : (v > hi ? hi : v); }
__device__ __forceinline__ unsigned short f2bf(float f) {
    unsigned u = __float_as_uint(f);
    unsigned r = (u + 0x7fffu + ((u >> 16) & 1u)) >> 16;   // RNE
    return (unsigned short)r;
}

// ---------------- CSR build ----------------
__global__ void count_kernel(const int* __restrict__ dst, int* __restrict__ cnt, int E, int n) {
    int e = blockIdx.x * blockDim.x + threadIdx.x;
    if (e < E) {
        int d = clampi(dst[e], 0, n - 1);
        atomicAdd(&cnt[d], 1);
    }
}

__global__ void scan_kernel(const int* __restrict__ cnt, int* __restrict__ cursor, int n) {
    __shared__ int sh[1024];
    const int tid = threadIdx.x;
    const int per = (n + 1023) >> 10;
    const int b = tid * per;
    int s = 0;
    for (int i = 0; i < per; ++i) { int idx = b + i; if (idx < n) s += cnt[idx]; }
    sh[tid] = s;
    __syncthreads();
    for (int off = 1; off < 1024; off <<= 1) {
        int u = (tid >= off) ? sh[tid - off] : 0;
        __syncthreads();
        if (tid >= off) sh[tid] += u;
        __syncthreads();
    }
    int run = sh[tid] - s;
    for (int i = 0; i < per; ++i) {
        int idx = b + i;
        if (idx < n) { cursor[idx] = run; run += cnt[idx]; }
    }
}

__global__ void bucket_kernel(const int* __restrict__ src, const int* __restrict__ dst,
                              const float* __restrict__ ew, int* __restrict__ cursor,
                              int* __restrict__ srcS, int* __restrict__ dstS,
                              float* __restrict__ wS, int E, int n) {
    int e = blockIdx.x * blockDim.x + threadIdx.x;
    if (e < E) {
        int d = clampi(dst[e], 0, n - 1);
        int s = clampi(src[e], 0, n - 1);
        int p = atomicAdd(&cursor[d], 1);
        srcS[p] = s; dstS[p] = d; wS[p] = ew[e];
    }
}

// ---------------- conversions ----------------
__global__ void cvt_x_kernel(const float* __restrict__ x, unsigned short* __restrict__ xb, int n8) {
    int i = blockIdx.x * blockDim.x + threadIdx.x;
    if (i >= n8) return;
    const float4* xp = (const float4*)x;
    float4 a = xp[2 * i], b = xp[2 * i + 1];
    ushort8v o;
    o[0] = f2bf(a.x); o[1] = f2bf(a.y); o[2] = f2bf(a.z); o[3] = f2bf(a.w);
    o[4] = f2bf(b.x); o[5] = f2bf(b.y); o[6] = f2bf(b.z); o[7] = f2bf(b.w);
    ((ushort8v*)xb)[i] = o;
}

// wtT[d][k] = bf16(w[k][d]) for the 128x128 top half of msg_w
__global__ void cvt_wt_kernel(const float* __restrict__ w, unsigned short* __restrict__ wtT) {
    int tid = blockIdx.x * blockDim.x + threadIdx.x;  // 16384
    int d = tid >> 7, k = tid & 127;
    wtT[d * 128 + k] = f2bf(w[k * 128 + d]);
}

// ---------------- per-node dst-half precompute: tdst = x @ W_bot + msg_b ----------------
__global__ __launch_bounds__(256) void pre_tdst_kernel(
    const float* __restrict__ x, const float* __restrict__ wbot,
    const float* __restrict__ bias, float* __restrict__ tdst, int n)
{
    __shared__ float Ws[128 * 128];
    __shared__ float xs[64 * 132];
    const int tid = threadIdx.x;
    const int r0 = blockIdx.x * 64;
    {
        const float4* wg = (const float4*)wbot;
        float4* wl = (float4*)Ws;
        for (int i = tid; i < 4096; i += 256) wl[i] = wg[i];
    }
    {
        int r = tid >> 2;
        int rr = imin(r0 + r, n - 1);
        int c0 = (tid & 3) * 32;
        const float4* xr = (const float4*)(x + (size_t)rr * H + c0);
        float4* dp = (float4*)&xs[r * 132 + c0];
        #pragma unroll
        for (int i = 0; i < 8; ++i) dp[i] = xr[i];
    }
    __syncthreads();
    float acc[8][4];
    #pragma unroll
    for (int i = 0; i < 8; ++i) { acc[i][0] = 0.f; acc[i][1] = 0.f; acc[i][2] = 0.f; acc[i][3] = 0.f; }
    const int eg = (tid >> 5) * 8;
    const int dg = (tid & 31) * 4;
    #pragma unroll 4
    for (int k = 0; k < 128; ++k) {
        float4 wv = *(const float4*)&Ws[k * 128 + dg];
        #pragma unroll
        for (int i = 0; i < 8; ++i) {
            float xv = xs[(eg + i) * 132 + k];
            acc[i][0] = fmaf(xv, wv.x, acc[i][0]);
            acc[i][1] = fmaf(xv, wv.y, acc[i][1]);
            acc[i][2] = fmaf(xv, wv.z, acc[i][2]);
            acc[i][3] = fmaf(xv, wv.w, acc[i][3]);
        }
    }
    float4 bb = *(const float4*)(bias + dg);
    #pragma unroll
    for (int i = 0; i < 8; ++i) {
        int row = r0 + eg + i;
        if (row < n) {
            float4 o;
            o.x = acc[i][0] + bb.x; o.y = acc[i][1] + bb.y;
            o.z = acc[i][2] + bb.z; o.w = acc[i][3] + bb.w;
            *(float4*)&tdst[(size_t)row * H + dg] = o;
        }
    }
}

// ---------------- per-edge MFMA: t = xb[src]@Wtop + tdst[dst]; LN->relu->*w -> segmented scatter ----------------
__global__ __launch_bounds__(256) void edge_msg_mfma(
    const unsigned short* __restrict__ xb,   // [n][128] bf16
    const int* __restrict__ srcS, const int* __restrict__ dstS,
    const float* __restrict__ wS,
    const unsigned short* __restrict__ wtT,  // [128][128] bf16, [d][k]
    const float* __restrict__ tdst,
    const float* __restrict__ gamma, const float* __restrict__ beta,
    float* __restrict__ msgs, int E)
{
    __shared__ unsigned short Wt[16384];   // 32 KB, XOR-swizzled: byte ^= (d&7)<<4
    __shared__ float tS[64 * 130];         // 33.3 KB
    __shared__ int   dst_s[64];
    __shared__ float w_s[64];

    const int tid  = threadIdx.x;
    const int e0   = blockIdx.x * 64;
    const int lane = tid & 63;
    const int wv   = tid >> 6;

    // stage swizzled Wt: 2048 chunks of 16B
    {
        const ushort8v* srcp = (const ushort8v*)wtT;
        for (int c = tid; c < 2048; c += 256) {
            int d = c >> 4, slot = c & 15;
            int off = d * 256 + ((slot * 16) ^ ((d & 7) << 4));
            *(ushort8v*)((char*)Wt + off) = srcp[c];
        }
    }
    if (tid < 64) {
        int e = e0 + tid;
        if (e < E) { dst_s[tid] = dstS[e]; w_s[tid] = wS[e]; }
        else       { dst_s[tid] = -1;      w_s[tid] = 0.f; }
    }
    // A-fragment source: lane covers edge row (lane&15) of this wave's 16-edge slice
    int my_e = e0 + wv * 16 + (lane & 15);
    int my_src = (my_e < E) ? srcS[my_e] : 0;
    const char* arow = (const char*)(xb + (size_t)my_src * H) + ((lane >> 4) * 16);
    __syncthreads();

    f32x4 acc[8];
    #pragma unroll
    for (int t = 0; t < 8; ++t) acc[t] = (f32x4){0.f, 0.f, 0.f, 0.f};

    const int dbase = lane & 15;
    const int kgrp  = lane >> 4;
    #pragma unroll
    for (int s = 0; s < 4; ++s) {
        bf16x8 a = *(const bf16x8*)(arow + s * 64);
        #pragma unroll
        for (int t = 0; t < 8; ++t) {
            int d = t * 16 + dbase;
            int off = d * 256 + ((s * 64 + kgrp * 16) ^ ((d & 7) << 4));
            bf16x8 b = *(const bf16x8*)((const char*)Wt + off);
            acc[t] = __builtin_amdgcn_mfma_f32_16x16x32_bf16(a, b, acc[t], 0, 0, 0);
        }
    }

    // epilogue: lane holds D rows (kgrp*4+r), col t*16+dbase
    float g_[8], b_[8];
    #pragma unroll
    for (int t = 0; t < 8; ++t) { g_[t] = gamma[t * 16 + dbase]; b_[t] = beta[t * 16 + dbase]; }

    #pragma unroll
    for (int r = 0; r < 4; ++r) {
        int el = wv * 16 + kgrp * 4 + r;
        int dn = dst_s[el];
        const float* td = tdst + (size_t)(dn < 0 ? 0 : dn) * H + dbase;
        float v[8];
        float sum = 0.f, sq = 0.f;
        #pragma unroll
        for (int t = 0; t < 8; ++t) {
            float val = acc[t][r] + td[t * 16];
            v[t] = val;
            sum += val;
            sq = fmaf(val, val, sq);
        }
        // reduce over the 16 lanes sharing kgrp (dims partitioned by dbase)
        sum += __shfl_xor(sum, 1); sq += __shfl_xor(sq, 1);
        sum += __shfl_xor(sum, 2); sq += __shfl_xor(sq, 2);
        sum += __shfl_xor(sum, 4); sq += __shfl_xor(sq, 4);
        sum += __shfl_xor(sum, 8); sq += __shfl_xor(sq, 8);
        float mu  = sum * (1.f / 128.f);
        float var = sq * (1.f / 128.f) - mu * mu;
        float ri  = rsqrtf(fmaxf(var, 0.f) + LN_EPS);
        float w   = w_s[el];
        #pragma unroll
        for (int t = 0; t < 8; ++t) {
            float val = fmaf((v[t] - mu) * ri, g_[t], b_[t]);
            val = fmaxf(val, 0.f) * w;
            tS[el * 130 + t * 16 + dbase] = val;
        }
    }
    __syncthreads();

    // segmented scatter over sorted-dst edges: thread owns dim d, scans 32 edges
    {
        int d = tid & 127;
        int h = tid >> 7;
        int eS = h * 32;
        int prev = dst_s[eS];
        float sum = 0.f;
        for (int i = 0; i < 32; ++i) {
            int e = eS + i;
            int dn = dst_s[e];
            if (dn != prev) {
                if (prev >= 0) atomicAdd(&msgs[(size_t)prev * H + d], sum);
                sum = 0.f; prev = dn;
            }
            sum += tS[e * 130 + d];
        }
        if (prev >= 0) atomicAdd(&msgs[(size_t)prev * H + d], sum);
    }
}

// ---------------- update: out = gate*relu(LN(x@Wu_top + messages@Wu_bot + b)) + (1-gate)*x ----------------
__global__ __launch_bounds__(256) void update_kernel(
    const float* __restrict__ x, const float* __restrict__ msgs,
    const int* __restrict__ cnt, const float* __restrict__ upd_w,
    const float* __restrict__ upd_b, const float* __restrict__ g,
    const float* __restrict__ beta, const float* __restrict__ gate_w,
    const float* __restrict__ gate_b, float* __restrict__ out, int n)
{
    __shared__ float Ws[128 * 128];
    __shared__ float xs[64 * 132];
    __shared__ float mt[64 * 132];
    __shared__ float gate_s[64], mu_s[64], ri_s[64];

    const int tid = threadIdx.x;
    const int r0 = blockIdx.x * 64;

    {
        int r = tid >> 2;
        int rr = imin(r0 + r, n - 1);
        int c0 = (tid & 3) * 32;
        const float4* xr = (const float4*)(x + (size_t)rr * H + c0);
        float4* dp = (float4*)&xs[r * 132 + c0];
        #pragma unroll
        for (int i = 0; i < 8; ++i) dp[i] = xr[i];
    }
    {
        const float4* wg = (const float4*)upd_w;
        float4* wl = (float4*)Ws;
        for (int i = tid; i < 4096; i += 256) wl[i] = wg[i];
    }
    {
        int r = tid >> 2;
        int rr = imin(r0 + r, n - 1);
        int c0 = (tid & 3) * 32;
        float c = (float)cnt[rr];
        float scale = (c > 0.f) ? 1.f / (c + 1e-8f) : 0.f;
        const float4* mr = (const float4*)(msgs + (size_t)rr * H + c0);
        float4* dp = (float4*)&mt[r * 132 + c0];
        #pragma unroll
        for (int i = 0; i < 8; ++i) {
            float4 v = mr[i];
            v.x *= scale; v.y *= scale; v.z *= scale; v.w *= scale;
            dp[i] = v;
        }
    }
    __syncthreads();
    {
        int r = tid >> 2;
        int q = tid & 3;
        const float* gw = gate_w + q * 32;
        const float* xr = &xs[r * 132 + q * 32];
        float s = 0.f;
        #pragma unroll 8
        for (int i = 0; i < 32; ++i) s = fmaf(xr[i], gw[i], s);
        s += __shfl_xor(s, 1); s += __shfl_xor(s, 2);
        if (q == 0) gate_s[r] = 1.f / (1.f + expf(-(s + gate_b[0])));
    }

    float acc[8][4];
    #pragma unroll
    for (int i = 0; i < 8; ++i) { acc[i][0] = 0.f; acc[i][1] = 0.f; acc[i][2] = 0.f; acc[i][3] = 0.f; }
    const int eg = (tid >> 5) * 8;
    const int dg = (tid & 31) * 4;
    #pragma unroll 4
    for (int k = 0; k < 128; ++k) {
        float4 wv = *(const float4*)&Ws[k * 128 + dg];
        #pragma unroll
        for (int i = 0; i < 8; ++i) {
            float xv = xs[(eg + i) * 132 + k];
            acc[i][0] = fmaf(xv, wv.x, acc[i][0]);
            acc[i][1] = fmaf(xv, wv.y, acc[i][1]);
            acc[i][2] = fmaf(xv, wv.z, acc[i][2]);
            acc[i][3] = fmaf(xv, wv.w, acc[i][3]);
        }
    }
    __syncthreads();
    {
        const float4* wg = (const float4*)(upd_w + 16384);
        float4* wl = (float4*)Ws;
        for (int i = tid; i < 4096; i += 256) wl[i] = wg[i];
    }
    __syncthreads();
    #pragma unroll 4
    for (int k = 0; k < 128; ++k) {
        float4 wv = *(const float4*)&Ws[k * 128 + dg];
        #pragma unroll
        for (int i = 0; i < 8; ++i) {
            float xv = mt[(eg + i) * 132 + k];
            acc[i][0] = fmaf(xv, wv.x, acc[i][0]);
            acc[i][1] = fmaf(xv, wv.y, acc[i][1]);
            acc[i][2] = fmaf(xv, wv.z, acc[i][2]);
            acc[i][3] = fmaf(xv, wv.w, acc[i][3]);
        }
    }
    __syncthreads();
    float4 ub = *(const float4*)(upd_b + dg);
    #pragma unroll
    for (int i = 0; i < 8; ++i) {
        mt[(eg + i) * 129 + dg + 0] = acc[i][0] + ub.x;
        mt[(eg + i) * 129 + dg + 1] = acc[i][1] + ub.y;
        mt[(eg + i) * 129 + dg + 2] = acc[i][2] + ub.z;
        mt[(eg + i) * 129 + dg + 3] = acc[i][3] + ub.w;
    }
    __syncthreads();
    {
        int r = tid >> 2;
        int q = tid & 3;
        int d0 = q * 32;
        float s = 0.f, s2 = 0.f;
        #pragma unroll 8
        for (int i = 0; i < 32; ++i) {
            float v = mt[r * 129 + d0 + i];
            s += v;
            s2 = fmaf(v, v, s2);
        }
        s  += __shfl_xor(s, 1);  s  += __shfl_xor(s, 2);
        s2 += __shfl_xor(s2, 1); s2 += __shfl_xor(s2, 2);
        if (q == 0) {
            float mu = s * (1.f / 128.f);
            float var = s2 * (1.f / 128.f) - mu * mu;
            mu_s[r] = mu;
            ri_s[r] = rsqrtf(fmaxf(var, 0.f) + LN_EPS);
        }
    }
    __syncthreads();
    {
        int d = tid & 127;
        int h = tid >> 7;
        float gd = g[d], bd = beta[d];
        for (int i = 0; i < 32; ++i) {
            int r = h * 32 + i;
            int row = r0 + r;
            if (row < n) {
                float v = fmaf((mt[r * 129 + d] - mu_s[r]) * ri_s[r], gd, bd);
                v = fmaxf(v, 0.f);
                float gt = gate_s[r];
                float xv = xs[r * 132 + d];
                out[(size_t)row * H + d] = fmaf(gt, v - xv, xv);
            }
        }
    }
}

extern "C" void kernel_launch(void* const* d_in, const int* in_sizes, int n_in,
                              void* d_out, int out_size, void* d_ws, size_t ws_size,
                              hipStream_t stream)
{
    const float* x        = (const float*)d_in[0];
    const int*   ei       = (const int*)d_in[1];
    const float* ew       = (const float*)d_in[2];
    const float* msg_w    = (const float*)d_in[3];
    const float* msg_b    = (const float*)d_in[4];
    const float* msg_g    = (const float*)d_in[5];
    const float* msg_beta = (const float*)d_in[6];
    const float* upd_w    = (const float*)d_in[7];
    const float* upd_b    = (const float*)d_in[8];
    const float* upd_g    = (const float*)d_in[9];
    const float* upd_beta = (const float*)d_in[10];
    const float* gate_w   = (const float*)d_in[11];
    const float* gate_b   = (const float*)d_in[12];

    const int n = in_sizes[0] / H;
    const int E = in_sizes[2];
    const int* src = ei;
    const int* dst = ei + E;

    char* p = (char*)d_ws;
    auto alloc = [&](size_t bytes) { char* r = p; p += (bytes + 255) & ~(size_t)255; return r; };
    int*   cnt    = (int*)alloc((size_t)n * 4);
    int*   cursor = (int*)alloc((size_t)n * 4);
    int*   srcS   = (int*)alloc((size_t)E * 4);
    int*   dstS   = (int*)alloc((size_t)E * 4);
    float* wS     = (float*)alloc((size_t)E * 4);
    float* tdst   = (float*)alloc((size_t)n * H * 4);
    float* msgs   = (float*)alloc((size_t)n * H * 4);
    unsigned short* xb  = (unsigned short*)alloc((size_t)n * H * 2);
    unsigned short* wtT = (unsigned short*)alloc((size_t)H * H * 2);

    hipMemsetAsync(cnt, 0, (size_t)n * 4, stream);
    hipMemsetAsync(msgs, 0, (size_t)n * H * 4, stream);

    int eb = (E + 255) / 256;
    count_kernel<<<eb, 256, 0, stream>>>(dst, cnt, E, n);
    scan_kernel<<<1, 1024, 0, stream>>>(cnt, cursor, n);
    bucket_kernel<<<eb, 256, 0, stream>>>(src, dst, ew, cursor, srcS, dstS, wS, E, n);

    int n8 = n * H / 8;
    cvt_x_kernel<<<(n8 + 255) / 256, 256, 0, stream>>>(x, xb, n8);
    cvt_wt_kernel<<<64, 256, 0, stream>>>(msg_w, wtT);

    pre_tdst_kernel<<<(n + 63) / 64, 256, 0, stream>>>(x, msg_w + 128 * H, msg_b, tdst, n);
    edge_msg_mfma<<<(E + 63) / 64, 256, 0, stream>>>(xb, srcS, dstS, wS, wtT, tdst, msg_g, msg_beta, msgs, E);
    update_kernel<<<(n + 63) / 64, 256, 0, stream>>>(x, msgs, cnt, upd_w, upd_b, upd_g, upd_beta, gate_w, gate_b, (float*)d_out, n);
}

// Round 3
// 357.518 us; speedup vs baseline: 3.0103x; 1.4802x over previous
//
#include <hip/hip_runtime.h>
#include <math.h>

#define H 128
#define LN_EPS 1e-5f

typedef __attribute__((ext_vector_type(8))) short  bf16x8;
typedef __attribute__((ext_vector_type(4))) float  f32x4;
typedef __attribute__((ext_vector_type(8))) unsigned short ushort8v;

__device__ __forceinline__ int imin(int a, int b) { return a < b ? a : b; }
__device__ __forceinline__ int clampi(int v, int lo, int hi) { return v < lo ? lo : (v > hi ? hi : v); }
__device__ __forceinline__ unsigned short f2bf(float f) {
    unsigned u = __float_as_uint(f);
    unsigned r = (u + 0x7fffu + ((u >> 16) & 1u)) >> 16;   // RNE
    return (unsigned short)r;
}
__device__ __forceinline__ float bf2f(unsigned short u) {
    return __uint_as_float(((unsigned)u) << 16);
}

// ---------------- CSR build ----------------
__global__ void count_kernel(const int* __restrict__ dst, int* __restrict__ cnt, int E, int n) {
    int e = blockIdx.x * blockDim.x + threadIdx.x;
    if (e < E) {
        int d = clampi(dst[e], 0, n - 1);
        atomicAdd(&cnt[d], 1);
    }
}

__global__ void scan_kernel(const int* __restrict__ cnt, int* __restrict__ cursor, int n) {
    __shared__ int sh[1024];
    const int tid = threadIdx.x;
    const int per = (n + 1023) >> 10;
    const int b = tid * per;
    int s = 0;
    for (int i = 0; i < per; ++i) { int idx = b + i; if (idx < n) s += cnt[idx]; }
    sh[tid] = s;
    __syncthreads();
    for (int off = 1; off < 1024; off <<= 1) {
        int u = (tid >= off) ? sh[tid - off] : 0;
        __syncthreads();
        if (tid >= off) sh[tid] += u;
        __syncthreads();
    }
    int run = sh[tid] - s;
    for (int i = 0; i < per; ++i) {
        int idx = b + i;
        if (idx < n) { cursor[idx] = run; run += cnt[idx]; }
    }
}

__global__ void bucket_kernel(const int* __restrict__ src, const int* __restrict__ dst,
                              const float* __restrict__ ew, int* __restrict__ cursor,
                              int* __restrict__ srcS, int* __restrict__ dstS,
                              float* __restrict__ wS, int E, int n) {
    int e = blockIdx.x * blockDim.x + threadIdx.x;
    if (e < E) {
        int d = clampi(dst[e], 0, n - 1);
        int s = clampi(src[e], 0, n - 1);
        int p = atomicAdd(&cursor[d], 1);
        srcS[p] = s; dstS[p] = d; wS[p] = ew[e];
    }
}

// ---------------- weight conversion: transpose + bf16 all four 128x128 blocks ----------------
__global__ void cvt_weights(const float* __restrict__ msg_w, const float* __restrict__ upd_w,
                            unsigned short* __restrict__ wtT, unsigned short* __restrict__ wbT,
                            unsigned short* __restrict__ wuT) {
    int tid = blockIdx.x * blockDim.x + threadIdx.x;   // 65536
    int m = tid >> 14;
    int r = tid & 16383;
    int d = r >> 7, k = r & 127;
    float v;
    unsigned short* dstp;
    if (m == 0)      { v = msg_w[k * 128 + d];          dstp = wtT; }
    else if (m == 1) { v = msg_w[(128 + k) * 128 + d];  dstp = wbT; }
    else if (m == 2) { v = upd_w[k * 128 + d];          dstp = wuT; }
    else             { v = upd_w[(128 + k) * 128 + d];  dstp = wuT + 16384; }
    dstp[d * 128 + k] = f2bf(v);
}

// ---------------- pre: tdstb = bf16(x @ W_bot + msg_b); also emits xb = bf16(x) ----------------
__global__ __launch_bounds__(256) void pre_tdst_mfma(
    const float* __restrict__ x, const unsigned short* __restrict__ wbT,
    const float* __restrict__ bias, unsigned short* __restrict__ xb,
    unsigned short* __restrict__ tdstb, int n)
{
    __shared__ unsigned short Wb[16384];
    const int tid = threadIdx.x, lane = tid & 63, wv = tid >> 6;
    const int dbase = lane & 15, kgrp = lane >> 4;
    const int swzl = (dbase & 7) << 4;
    const int r0 = blockIdx.x * 64;

    {
        const ushort8v* srcp = (const ushort8v*)wbT;
        for (int c = tid; c < 2048; c += 256) {
            int d = c >> 4, slot = c & 15;
            int off = d * 256 + ((slot * 16) ^ ((d & 7) << 4));
            *(ushort8v*)((char*)Wb + off) = srcp[c];
        }
    }

    int rowA = imin(r0 + wv * 16 + dbase, n - 1);
    bf16x8 a[4];
    {
        const float* xr = x + (size_t)rowA * H + kgrp * 8;
        #pragma unroll
        for (int s = 0; s < 4; ++s) {
            float4 f0 = *(const float4*)(xr + s * 32);
            float4 f1 = *(const float4*)(xr + s * 32 + 4);
            bf16x8 v;
            v[0] = (short)f2bf(f0.x); v[1] = (short)f2bf(f0.y);
            v[2] = (short)f2bf(f0.z); v[3] = (short)f2bf(f0.w);
            v[4] = (short)f2bf(f1.x); v[5] = (short)f2bf(f1.y);
            v[6] = (short)f2bf(f1.z); v[7] = (short)f2bf(f1.w);
            a[s] = v;
            *(bf16x8*)(xb + (size_t)rowA * H + s * 32 + kgrp * 8) = v;
        }
    }
    __syncthreads();

    f32x4 acc[8];
    #pragma unroll
    for (int t = 0; t < 8; ++t) acc[t] = (f32x4){0.f, 0.f, 0.f, 0.f};
    #pragma unroll
    for (int s = 0; s < 4; ++s) {
        #pragma unroll
        for (int t = 0; t < 8; ++t) {
            int off = (t * 16 + dbase) * 256 + ((s * 64 + kgrp * 16) ^ swzl);
            bf16x8 b = *(const bf16x8*)((const char*)Wb + off);
            acc[t] = __builtin_amdgcn_mfma_f32_16x16x32_bf16(a[s], b, acc[t], 0, 0, 0);
        }
    }

    float ub[8];
    #pragma unroll
    for (int t = 0; t < 8; ++t) ub[t] = bias[t * 16 + dbase];
    #pragma unroll
    for (int r = 0; r < 4; ++r) {
        int row = r0 + wv * 16 + kgrp * 4 + r;
        if (row < n) {
            #pragma unroll
            for (int t = 0; t < 8; ++t)
                tdstb[(size_t)row * H + t * 16 + dbase] = f2bf(acc[t][r] + ub[t]);
        }
    }
}

// ---------------- per-edge MFMA, persistent grid-stride with cross-tile prefetch ----------------
__global__ __launch_bounds__(256) void edge_msg_mfma(
    const unsigned short* __restrict__ xb,
    const int* __restrict__ srcS, const int* __restrict__ dstS,
    const float* __restrict__ wS,
    const unsigned short* __restrict__ wtT,
    const unsigned short* __restrict__ tdstb,
    const float* __restrict__ gamma, const float* __restrict__ beta,
    float* __restrict__ msgs, int E, int ntiles)
{
    __shared__ unsigned short Wt[16384];   // 32 KB, XOR-swizzled
    __shared__ float tS[64 * 130];         // 33.3 KB
    __shared__ int   dst_s[64];
    __shared__ float w_s[64];

    const int tid  = threadIdx.x;
    const int lane = tid & 63;
    const int wv   = tid >> 6;
    const int dbase = lane & 15;
    const int kgrp  = lane >> 4;
    const int swzl  = (dbase & 7) << 4;

    {
        const ushort8v* srcp = (const ushort8v*)wtT;
        for (int c = tid; c < 2048; c += 256) {
            int d = c >> 4, slot = c & 15;
            int off = d * 256 + ((slot * 16) ^ ((d & 7) << 4));
            *(ushort8v*)((char*)Wt + off) = srcp[c];
        }
    }
    float g_[8], b_[8];
    #pragma unroll
    for (int t = 0; t < 8; ++t) { g_[t] = gamma[t * 16 + dbase]; b_[t] = beta[t * 16 + dbase]; }

    // prologue: first tile's meta + A-fragments
    int tile = blockIdx.x;
    int mdst = -1; float mw = 0.f; int msrc = 0;
    if (tile < ntiles) {
        int e0 = tile * 64;
        if (tid < 64) {
            int e = e0 + tid;
            if (e < E) { mdst = dstS[e]; mw = wS[e]; }
        }
        int my_e = e0 + wv * 16 + dbase;
        if (my_e < E) msrc = srcS[my_e];
    }
    bf16x8 a[4];
    {
        const char* arow = (const char*)(xb + (size_t)msrc * H) + kgrp * 16;
        #pragma unroll
        for (int s = 0; s < 4; ++s) a[s] = *(const bf16x8*)(arow + s * 64);
    }

    for (; tile < ntiles; tile += gridDim.x) {
        __syncthreads();                        // prev tile's tS/dst_s readers done
        if (tid < 64) { dst_s[tid] = mdst; w_s[tid] = mw; }
        __syncthreads();                        // publish (also covers Wt staging, 1st iter)

        // prefetch next tile's meta
        int tn = tile + gridDim.x;
        int ndst = -1; float nw = 0.f; int nsrc = 0;
        if (tn < ntiles) {
            int e0n = tn * 64;
            if (tid < 64) {
                int e = e0n + tid;
                if (e < E) { ndst = dstS[e]; nw = wS[e]; }
            }
            int my_en = e0n + wv * 16 + dbase;
            if (my_en < E) nsrc = srcS[my_en];
        }

        f32x4 acc[8];
        #pragma unroll
        for (int t = 0; t < 8; ++t) acc[t] = (f32x4){0.f, 0.f, 0.f, 0.f};
        #pragma unroll
        for (int s = 0; s < 4; ++s) {
            #pragma unroll
            for (int t = 0; t < 8; ++t) {
                int off = (t * 16 + dbase) * 256 + ((s * 64 + kgrp * 16) ^ swzl);
                bf16x8 b = *(const bf16x8*)((const char*)Wt + off);
                acc[t] = __builtin_amdgcn_mfma_f32_16x16x32_bf16(a[s], b, acc[t], 0, 0, 0);
            }
        }

        // prefetch next tile's A-fragments (hide gather latency under epilogue+scatter)
        bf16x8 an[4];
        {
            const char* arow = (const char*)(xb + (size_t)nsrc * H) + kgrp * 16;
            #pragma unroll
            for (int s = 0; s < 4; ++s) an[s] = *(const bf16x8*)(arow + s * 64);
        }

        // epilogue: LN -> relu -> *w into tS
        #pragma unroll
        for (int r = 0; r < 4; ++r) {
            int el = wv * 16 + kgrp * 4 + r;
            int dn = dst_s[el];
            const unsigned short* td = tdstb + (size_t)(dn < 0 ? 0 : dn) * H + dbase;
            float v[8];
            float sum = 0.f, sq = 0.f;
            #pragma unroll
            for (int t = 0; t < 8; ++t) {
                float val = acc[t][r] + bf2f(td[t * 16]);
                v[t] = val;
                sum += val;
                sq = fmaf(val, val, sq);
            }
            sum += __shfl_xor(sum, 1); sq += __shfl_xor(sq, 1);
            sum += __shfl_xor(sum, 2); sq += __shfl_xor(sq, 2);
            sum += __shfl_xor(sum, 4); sq += __shfl_xor(sq, 4);
            sum += __shfl_xor(sum, 8); sq += __shfl_xor(sq, 8);
            float mu  = sum * (1.f / 128.f);
            float var = sq * (1.f / 128.f) - mu * mu;
            float ri  = rsqrtf(fmaxf(var, 0.f) + LN_EPS);
            float w   = w_s[el];
            #pragma unroll
            for (int t = 0; t < 8; ++t) {
                float val = fmaf((v[t] - mu) * ri, g_[t], b_[t]);
                tS[el * 130 + t * 16 + dbase] = fmaxf(val, 0.f) * w;
            }
        }
        __syncthreads();

        // segmented scatter
        {
            int d = tid & 127;
            int h = tid >> 7;
            int eS = h * 32;
            int prev = dst_s[eS];
            float sum = 0.f;
            for (int i = 0; i < 32; ++i) {
                int e = eS + i;
                int dn = dst_s[e];
                if (dn != prev) {
                    if (prev >= 0) atomicAdd(&msgs[(size_t)prev * H + d], sum);
                    sum = 0.f; prev = dn;
                }
                sum += tS[e * 130 + d];
            }
            if (prev >= 0) atomicAdd(&msgs[(size_t)prev * H + d], sum);
        }

        // rotate prefetched state
        mdst = ndst; mw = nw; msrc = nsrc;
        a[0] = an[0]; a[1] = an[1]; a[2] = an[2]; a[3] = an[3];
    }
}

// ---------------- update via MFMA: out = gate*relu(LN(x@Wt + m@Wb + b)) + (1-gate)*x ----------------
__global__ __launch_bounds__(256) void update_mfma(
    const float* __restrict__ x, const unsigned short* __restrict__ xb,
    const float* __restrict__ msgs, const int* __restrict__ cnt,
    const unsigned short* __restrict__ wuT,   // [2][128][128] bf16 [m][d][k]
    const float* __restrict__ upd_b, const float* __restrict__ g,
    const float* __restrict__ beta, const float* __restrict__ gate_w,
    const float* __restrict__ gate_b, float* __restrict__ out, int n)
{
    __shared__ unsigned short W2[2][16384];   // 64 KB
    const int tid = threadIdx.x, lane = tid & 63, wv = tid >> 6;
    const int dbase = lane & 15, kgrp = lane >> 4;
    const int swzl = (dbase & 7) << 4;
    const int r0 = blockIdx.x * 64;

    {
        const ushort8v* srcp = (const ushort8v*)wuT;
        for (int c = tid; c < 4096; c += 256) {
            int m = c >> 11, c2 = c & 2047;
            int d = c2 >> 4, slot = c2 & 15;
            int off = m * 32768 + d * 256 + ((slot * 16) ^ ((d & 7) << 4));
            *(ushort8v*)((char*)W2 + off) = srcp[c];
        }
    }

    int rowA = imin(r0 + wv * 16 + dbase, n - 1);
    bf16x8 ax[4], am[4];
    {
        const char* arow = (const char*)(xb + (size_t)rowA * H) + kgrp * 16;
        #pragma unroll
        for (int s = 0; s < 4; ++s) ax[s] = *(const bf16x8*)(arow + s * 64);
    }
    {
        float c = (float)cnt[rowA];
        float scale = (c > 0.f) ? 1.f / (c + 1e-8f) : 0.f;
        const float* mr = msgs + (size_t)rowA * H + kgrp * 8;
        #pragma unroll
        for (int s = 0; s < 4; ++s) {
            float4 f0 = *(const float4*)(mr + s * 32);
            float4 f1 = *(const float4*)(mr + s * 32 + 4);
            bf16x8 v;
            v[0] = (short)f2bf(f0.x * scale); v[1] = (short)f2bf(f0.y * scale);
            v[2] = (short)f2bf(f0.z * scale); v[3] = (short)f2bf(f0.w * scale);
            v[4] = (short)f2bf(f1.x * scale); v[5] = (short)f2bf(f1.y * scale);
            v[6] = (short)f2bf(f1.z * scale); v[7] = (short)f2bf(f1.w * scale);
            am[s] = v;
        }
    }
    __syncthreads();

    f32x4 acc[8];
    #pragma unroll
    for (int t = 0; t < 8; ++t) acc[t] = (f32x4){0.f, 0.f, 0.f, 0.f};
    #pragma unroll
    for (int s = 0; s < 4; ++s) {
        #pragma unroll
        for (int t = 0; t < 8; ++t) {
            int off = (t * 16 + dbase) * 256 + ((s * 64 + kgrp * 16) ^ swzl);
            bf16x8 b = *(const bf16x8*)((const char*)W2 + off);
            acc[t] = __builtin_amdgcn_mfma_f32_16x16x32_bf16(ax[s], b, acc[t], 0, 0, 0);
        }
    }
    #pragma unroll
    for (int s = 0; s < 4; ++s) {
        #pragma unroll
        for (int t = 0; t < 8; ++t) {
            int off = 32768 + (t * 16 + dbase) * 256 + ((s * 64 + kgrp * 16) ^ swzl);
            bf16x8 b = *(const bf16x8*)((const char*)W2 + off);
            acc[t] = __builtin_amdgcn_mfma_f32_16x16x32_bf16(am[s], b, acc[t], 0, 0, 0);
        }
    }

    float ub[8], g_[8], be_[8], gw_[8];
    #pragma unroll
    for (int t = 0; t < 8; ++t) {
        int d = t * 16 + dbase;
        ub[t] = upd_b[d]; g_[t] = g[d]; be_[t] = beta[d]; gw_[t] = gate_w[d];
    }
    const float gb = gate_b[0];

    #pragma unroll
    for (int r = 0; r < 4; ++r) {
        int row = r0 + wv * 16 + kgrp * 4 + r;
        if (row >= n) continue;
        const float* xr = x + (size_t)row * H + dbase;
        float xf[8], v[8];
        float sum = 0.f, sq = 0.f, gs = 0.f;
        #pragma unroll
        for (int t = 0; t < 8; ++t) {
            xf[t] = xr[t * 16];
            float val = acc[t][r] + ub[t];
            v[t] = val;
            sum += val;
            sq = fmaf(val, val, sq);
            gs = fmaf(xf[t], gw_[t], gs);
        }
        sum += __shfl_xor(sum, 1); sq += __shfl_xor(sq, 1); gs += __shfl_xor(gs, 1);
        sum += __shfl_xor(sum, 2); sq += __shfl_xor(sq, 2); gs += __shfl_xor(gs, 2);
        sum += __shfl_xor(sum, 4); sq += __shfl_xor(sq, 4); gs += __shfl_xor(gs, 4);
        sum += __shfl_xor(sum, 8); sq += __shfl_xor(sq, 8); gs += __shfl_xor(gs, 8);
        float mu  = sum * (1.f / 128.f);
        float var = sq * (1.f / 128.f) - mu * mu;
        float ri  = rsqrtf(fmaxf(var, 0.f) + LN_EPS);
        float gate = 1.f / (1.f + expf(-(gs + gb)));
        float* orow = out + (size_t)row * H + dbase;
        #pragma unroll
        for (int t = 0; t < 8; ++t) {
            float h = fmaf((v[t] - mu) * ri, g_[t], be_[t]);
            h = fmaxf(h, 0.f);
            orow[t * 16] = fmaf(gate, h - xf[t], xf[t]);
        }
    }
}

extern "C" void kernel_launch(void* const* d_in, const int* in_sizes, int n_in,
                              void* d_out, int out_size, void* d_ws, size_t ws_size,
                              hipStream_t stream)
{
    const float* x        = (const float*)d_in[0];
    const int*   ei       = (const int*)d_in[1];
    const float* ew       = (const float*)d_in[2];
    const float* msg_w    = (const float*)d_in[3];
    const float* msg_b    = (const float*)d_in[4];
    const float* msg_g    = (const float*)d_in[5];
    const float* msg_beta = (const float*)d_in[6];
    const float* upd_w    = (const float*)d_in[7];
    const float* upd_b    = (const float*)d_in[8];
    const float* upd_g    = (const float*)d_in[9];
    const float* upd_beta = (const float*)d_in[10];
    const float* gate_w   = (const float*)d_in[11];
    const float* gate_b   = (const float*)d_in[12];

    const int n = in_sizes[0] / H;
    const int E = in_sizes[2];
    const int* src = ei;
    const int* dst = ei + E;

    char* p = (char*)d_ws;
    auto alloc = [&](size_t bytes) { char* r = p; p += (bytes + 255) & ~(size_t)255; return r; };
    int*   cnt    = (int*)alloc((size_t)n * 4);
    int*   cursor = (int*)alloc((size_t)n * 4);
    int*   srcS   = (int*)alloc((size_t)E * 4);
    int*   dstS   = (int*)alloc((size_t)E * 4);
    float* wS     = (float*)alloc((size_t)E * 4);
    float* msgs   = (float*)alloc((size_t)n * H * 4);
    unsigned short* xb    = (unsigned short*)alloc((size_t)n * H * 2);
    unsigned short* tdstb = (unsigned short*)alloc((size_t)n * H * 2);
    unsigned short* wtT   = (unsigned short*)alloc((size_t)H * H * 2);
    unsigned short* wbT   = (unsigned short*)alloc((size_t)H * H * 2);
    unsigned short* wuT   = (unsigned short*)alloc((size_t)2 * H * H * 2);

    hipMemsetAsync(cnt, 0, (size_t)n * 4, stream);
    hipMemsetAsync(msgs, 0, (size_t)n * H * 4, stream);

    int eb = (E + 255) / 256;
    count_kernel<<<eb, 256, 0, stream>>>(dst, cnt, E, n);
    scan_kernel<<<1, 1024, 0, stream>>>(cnt, cursor, n);
    bucket_kernel<<<eb, 256, 0, stream>>>(src, dst, ew, cursor, srcS, dstS, wS, E, n);

    cvt_weights<<<256, 256, 0, stream>>>(msg_w, upd_w, wtT, wbT, wuT);
    pre_tdst_mfma<<<(n + 63) / 64, 256, 0, stream>>>(x, wbT, msg_b, xb, tdstb, n);

    int ntiles = (E + 63) / 64;
    int eblocks = ntiles < 512 ? ntiles : 512;
    edge_msg_mfma<<<eblocks, 256, 0, stream>>>(xb, srcS, dstS, wS, wtT, tdstb, msg_g, msg_beta, msgs, E, ntiles);

    update_mfma<<<(n + 63) / 64, 256, 0, stream>>>(x, xb, msgs, cnt, wuT, upd_b, upd_g, upd_beta, gate_w, gate_b, (float*)d_out, n);
}

// Round 4
// 290.703 us; speedup vs baseline: 3.7022x; 1.2298x over previous
//
#include <hip/hip_runtime.h>
#include <math.h>

#define H 128
#define LN_EPS 1e-5f

typedef __attribute__((ext_vector_type(8))) short  bf16x8;
typedef __attribute__((ext_vector_type(4))) float  f32x4;
typedef __attribute__((ext_vector_type(8))) unsigned short ushort8v;

__device__ __forceinline__ int imin(int a, int b) { return a < b ? a : b; }
__device__ __forceinline__ int clampi(int v, int lo, int hi) { return v < lo ? lo : (v > hi ? hi : v); }
__device__ __forceinline__ unsigned short f2bf(float f) {
    unsigned u = __float_as_uint(f);
    unsigned r = (u + 0x7fffu + ((u >> 16) & 1u)) >> 16;   // RNE
    return (unsigned short)r;
}
__device__ __forceinline__ float bf2f(unsigned short u) {
    return __uint_as_float(((unsigned)u) << 16);
}

// ---------------- CSR build ----------------
__global__ void count_kernel(const int* __restrict__ dst, int* __restrict__ cnt, int E, int n) {
    int e = blockIdx.x * blockDim.x + threadIdx.x;
    if (e < E) {
        int d = clampi(dst[e], 0, n - 1);
        atomicAdd(&cnt[d], 1);
    }
}

__global__ void scan_kernel(const int* __restrict__ cnt, int* __restrict__ cursor, int n) {
    __shared__ int sh[1024];
    const int tid = threadIdx.x;
    const int per = (n + 1023) >> 10;
    const int b = tid * per;
    int s = 0;
    for (int i = 0; i < per; ++i) { int idx = b + i; if (idx < n) s += cnt[idx]; }
    sh[tid] = s;
    __syncthreads();
    for (int off = 1; off < 1024; off <<= 1) {
        int u = (tid >= off) ? sh[tid - off] : 0;
        __syncthreads();
        if (tid >= off) sh[tid] += u;
        __syncthreads();
    }
    int run = sh[tid] - s;
    for (int i = 0; i < per; ++i) {
        int idx = b + i;
        if (idx < n) { cursor[idx] = run; run += cnt[idx]; }
    }
}

// bucket: sorted-by-dst srcS and wS only (dst implicit via CSR)
__global__ void bucket_kernel(const int* __restrict__ src, const int* __restrict__ dst,
                              const float* __restrict__ ew, int* __restrict__ cursor,
                              int* __restrict__ srcS, float* __restrict__ wS, int E, int n) {
    int e = blockIdx.x * blockDim.x + threadIdx.x;
    if (e < E) {
        int d = clampi(dst[e], 0, n - 1);
        int s = clampi(src[e], 0, n - 1);
        int p = atomicAdd(&cursor[d], 1);
        srcS[p] = s; wS[p] = ew[e];
    }
}

// ---------------- weight conversion: transpose + bf16 all four 128x128 blocks ----------------
__global__ void cvt_weights(const float* __restrict__ msg_w, const float* __restrict__ upd_w,
                            unsigned short* __restrict__ wtT, unsigned short* __restrict__ wbT,
                            unsigned short* __restrict__ wuT) {
    int tid = blockIdx.x * blockDim.x + threadIdx.x;   // 65536
    int m = tid >> 14;
    int r = tid & 16383;
    int d = r >> 7, k = r & 127;
    float v;
    unsigned short* dstp;
    if (m == 0)      { v = msg_w[k * 128 + d];          dstp = wtT; }
    else if (m == 1) { v = msg_w[(128 + k) * 128 + d];  dstp = wbT; }
    else if (m == 2) { v = upd_w[k * 128 + d];          dstp = wuT; }
    else             { v = upd_w[(128 + k) * 128 + d];  dstp = wuT + 16384; }
    dstp[d * 128 + k] = f2bf(v);
}

// ---------------- pre: tsrcb = bf16(x@Wtop), tdstb = bf16(x@Wbot + msg_b), xb = bf16(x) ----------------
__global__ __launch_bounds__(256) void pre_both_mfma(
    const float* __restrict__ x,
    const unsigned short* __restrict__ wtT, const unsigned short* __restrict__ wbT,
    const float* __restrict__ bias, unsigned short* __restrict__ xb,
    unsigned short* __restrict__ tsrcb, unsigned short* __restrict__ tdstb, int n)
{
    __shared__ unsigned short Wt[16384];
    __shared__ unsigned short Wb[16384];
    const int tid = threadIdx.x, lane = tid & 63, wv = tid >> 6;
    const int dbase = lane & 15, kgrp = lane >> 4;
    const int swzl = (dbase & 7) << 4;
    const int r0 = blockIdx.x * 64;

    {
        const ushort8v* st = (const ushort8v*)wtT;
        const ushort8v* sb = (const ushort8v*)wbT;
        for (int c = tid; c < 2048; c += 256) {
            int d = c >> 4, slot = c & 15;
            int off = d * 256 + ((slot * 16) ^ ((d & 7) << 4));
            *(ushort8v*)((char*)Wt + off) = st[c];
            *(ushort8v*)((char*)Wb + off) = sb[c];
        }
    }

    int rowA = imin(r0 + wv * 16 + dbase, n - 1);
    bf16x8 a[4];
    {
        const float* xr = x + (size_t)rowA * H + kgrp * 8;
        #pragma unroll
        for (int s = 0; s < 4; ++s) {
            float4 f0 = *(const float4*)(xr + s * 32);
            float4 f1 = *(const float4*)(xr + s * 32 + 4);
            bf16x8 v;
            v[0] = (short)f2bf(f0.x); v[1] = (short)f2bf(f0.y);
            v[2] = (short)f2bf(f0.z); v[3] = (short)f2bf(f0.w);
            v[4] = (short)f2bf(f1.x); v[5] = (short)f2bf(f1.y);
            v[6] = (short)f2bf(f1.z); v[7] = (short)f2bf(f1.w);
            a[s] = v;
            *(bf16x8*)(xb + (size_t)rowA * H + s * 32 + kgrp * 8) = v;
        }
    }
    __syncthreads();

    f32x4 accT[8], accB[8];
    #pragma unroll
    for (int t = 0; t < 8; ++t) { accT[t] = (f32x4){0.f,0.f,0.f,0.f}; accB[t] = (f32x4){0.f,0.f,0.f,0.f}; }
    #pragma unroll
    for (int s = 0; s < 4; ++s) {
        #pragma unroll
        for (int t = 0; t < 8; ++t) {
            int off = (t * 16 + dbase) * 256 + ((s * 64 + kgrp * 16) ^ swzl);
            bf16x8 bt = *(const bf16x8*)((const char*)Wt + off);
            bf16x8 bb = *(const bf16x8*)((const char*)Wb + off);
            accT[t] = __builtin_amdgcn_mfma_f32_16x16x32_bf16(a[s], bt, accT[t], 0, 0, 0);
            accB[t] = __builtin_amdgcn_mfma_f32_16x16x32_bf16(a[s], bb, accB[t], 0, 0, 0);
        }
    }

    float ub[8];
    #pragma unroll
    for (int t = 0; t < 8; ++t) ub[t] = bias[t * 16 + dbase];
    #pragma unroll
    for (int r = 0; r < 4; ++r) {
        int row = r0 + wv * 16 + kgrp * 4 + r;
        if (row < n) {
            #pragma unroll
            for (int t = 0; t < 8; ++t) {
                tsrcb[(size_t)row * H + t * 16 + dbase] = f2bf(accT[t][r]);
                tdstb[(size_t)row * H + t * 16 + dbase] = f2bf(accB[t][r] + ub[t]);
            }
        }
    }
}

// ---------------- node-centric messages: msgs[v] = mean_e relu(LN(tsrc[src_e]+tdst[v]))*w_e ----------------
__global__ __launch_bounds__(256) void node_msg_kernel(
    const unsigned short* __restrict__ tsrcb,
    const unsigned short* __restrict__ tdstb,
    const int* __restrict__ srcS, const float* __restrict__ wS,
    const int* __restrict__ cnt, const int* __restrict__ endoff,
    const float* __restrict__ gamma, const float* __restrict__ beta,
    float* __restrict__ msgs, int n)
{
    const int tid  = threadIdx.x;
    const int lane = tid & 63;
    const int qq   = lane & 15;               // dims qq*8 .. qq*8+7
    const int node = blockIdx.x * 16 + (tid >> 4);
    if (node >= n) return;
    const int k   = cnt[node];
    const int end = endoff[node];
    int e = end - k;

    float td[8];
    {
        ushort8v t = *(const ushort8v*)(tdstb + (size_t)node * H + qq * 8);
        #pragma unroll
        for (int j = 0; j < 8; ++j) td[j] = bf2f((unsigned short)t[j]);
    }
    float g_[8], b_[8];
    #pragma unroll
    for (int j = 0; j < 8; ++j) { g_[j] = gamma[qq * 8 + j]; b_[j] = beta[qq * 8 + j]; }

    float acc[8];
    #pragma unroll
    for (int j = 0; j < 8; ++j) acc[j] = 0.f;

    ushort8v a_c = {};
    float w_c = 0.f;
    if (k > 0) {
        int s = srcS[e];
        w_c = wS[e];
        a_c = *(const ushort8v*)(tsrcb + (size_t)s * H + qq * 8);
    }
    for (int i = 0; i < k; ++i) {
        ushort8v a_n = {};
        float w_n = 0.f;
        if (i + 1 < k) {                       // prefetch next edge's row
            int s = srcS[e + 1];
            w_n = wS[e + 1];
            a_n = *(const ushort8v*)(tsrcb + (size_t)s * H + qq * 8);
        }
        float v[8], sum = 0.f, sq = 0.f;
        #pragma unroll
        for (int j = 0; j < 8; ++j) {
            v[j] = td[j] + bf2f((unsigned short)a_c[j]);
            sum += v[j];
            sq = fmaf(v[j], v[j], sq);
        }
        sum += __shfl_xor(sum, 1); sq += __shfl_xor(sq, 1);
        sum += __shfl_xor(sum, 2); sq += __shfl_xor(sq, 2);
        sum += __shfl_xor(sum, 4); sq += __shfl_xor(sq, 4);
        sum += __shfl_xor(sum, 8); sq += __shfl_xor(sq, 8);
        float mu  = sum * (1.f / 128.f);
        float var = sq * (1.f / 128.f) - mu * mu;
        float ri  = rsqrtf(fmaxf(var, 0.f) + LN_EPS);
        float nmr = -mu * ri;
        #pragma unroll
        for (int j = 0; j < 8; ++j) {
            float t = fmaf(v[j], ri, nmr);
            float val = fmaf(t, g_[j], b_[j]);
            acc[j] = fmaf(fmaxf(val, 0.f), w_c, acc[j]);
        }
        a_c = a_n; w_c = w_n; ++e;
    }
    float scale = (k > 0) ? 1.f / ((float)k + 1e-8f) : 0.f;
    float* orow = msgs + (size_t)node * H + qq * 8;
    float4 o0, o1;
    o0.x = acc[0] * scale; o0.y = acc[1] * scale; o0.z = acc[2] * scale; o0.w = acc[3] * scale;
    o1.x = acc[4] * scale; o1.y = acc[5] * scale; o1.z = acc[6] * scale; o1.w = acc[7] * scale;
    *(float4*)orow = o0;
    *(float4*)(orow + 4) = o1;
}

// ---------------- update via MFMA: out = gate*relu(LN(x@Wt + m@Wb + b)) + (1-gate)*x ----------------
__global__ __launch_bounds__(256) void update_mfma(
    const float* __restrict__ x, const unsigned short* __restrict__ xb,
    const float* __restrict__ msgs,
    const unsigned short* __restrict__ wuT,   // [2][128][128] bf16 [m][d][k]
    const float* __restrict__ upd_b, const float* __restrict__ g,
    const float* __restrict__ beta, const float* __restrict__ gate_w,
    const float* __restrict__ gate_b, float* __restrict__ out, int n)
{
    __shared__ unsigned short W2[2][16384];   // 64 KB
    const int tid = threadIdx.x, lane = tid & 63, wv = tid >> 6;
    const int dbase = lane & 15, kgrp = lane >> 4;
    const int swzl = (dbase & 7) << 4;
    const int r0 = blockIdx.x * 64;

    {
        const ushort8v* srcp = (const ushort8v*)wuT;
        for (int c = tid; c < 4096; c += 256) {
            int m = c >> 11, c2 = c & 2047;
            int d = c2 >> 4, slot = c2 & 15;
            int off = m * 32768 + d * 256 + ((slot * 16) ^ ((d & 7) << 4));
            *(ushort8v*)((char*)W2 + off) = srcp[c];
        }
    }

    int rowA = imin(r0 + wv * 16 + dbase, n - 1);
    bf16x8 ax[4], am[4];
    {
        const char* arow = (const char*)(xb + (size_t)rowA * H) + kgrp * 16;
        #pragma unroll
        for (int s = 0; s < 4; ++s) ax[s] = *(const bf16x8*)(arow + s * 64);
    }
    {
        const float* mr = msgs + (size_t)rowA * H + kgrp * 8;
        #pragma unroll
        for (int s = 0; s < 4; ++s) {
            float4 f0 = *(const float4*)(mr + s * 32);
            float4 f1 = *(const float4*)(mr + s * 32 + 4);
            bf16x8 v;
            v[0] = (short)f2bf(f0.x); v[1] = (short)f2bf(f0.y);
            v[2] = (short)f2bf(f0.z); v[3] = (short)f2bf(f0.w);
            v[4] = (short)f2bf(f1.x); v[5] = (short)f2bf(f1.y);
            v[6] = (short)f2bf(f1.z); v[7] = (short)f2bf(f1.w);
            am[s] = v;
        }
    }
    __syncthreads();

    f32x4 acc[8];
    #pragma unroll
    for (int t = 0; t < 8; ++t) acc[t] = (f32x4){0.f, 0.f, 0.f, 0.f};
    #pragma unroll
    for (int s = 0; s < 4; ++s) {
        #pragma unroll
        for (int t = 0; t < 8; ++t) {
            int off = (t * 16 + dbase) * 256 + ((s * 64 + kgrp * 16) ^ swzl);
            bf16x8 b = *(const bf16x8*)((const char*)W2 + off);
            acc[t] = __builtin_amdgcn_mfma_f32_16x16x32_bf16(ax[s], b, acc[t], 0, 0, 0);
        }
    }
    #pragma unroll
    for (int s = 0; s < 4; ++s) {
        #pragma unroll
        for (int t = 0; t < 8; ++t) {
            int off = 32768 + (t * 16 + dbase) * 256 + ((s * 64 + kgrp * 16) ^ swzl);
            bf16x8 b = *(const bf16x8*)((const char*)W2 + off);
            acc[t] = __builtin_amdgcn_mfma_f32_16x16x32_bf16(am[s], b, acc[t], 0, 0, 0);
        }
    }

    float ub[8], g_[8], be_[8], gw_[8];
    #pragma unroll
    for (int t = 0; t < 8; ++t) {
        int d = t * 16 + dbase;
        ub[t] = upd_b[d]; g_[t] = g[d]; be_[t] = beta[d]; gw_[t] = gate_w[d];
    }
    const float gb = gate_b[0];

    #pragma unroll
    for (int r = 0; r < 4; ++r) {
        int row = r0 + wv * 16 + kgrp * 4 + r;
        if (row >= n) continue;
        const float* xr = x + (size_t)row * H + dbase;
        float xf[8], v[8];
        float sum = 0.f, sq = 0.f, gs = 0.f;
        #pragma unroll
        for (int t = 0; t < 8; ++t) {
            xf[t] = xr[t * 16];
            float val = acc[t][r] + ub[t];
            v[t] = val;
            sum += val;
            sq = fmaf(val, val, sq);
            gs = fmaf(xf[t], gw_[t], gs);
        }
        sum += __shfl_xor(sum, 1); sq += __shfl_xor(sq, 1); gs += __shfl_xor(gs, 1);
        sum += __shfl_xor(sum, 2); sq += __shfl_xor(sq, 2); gs += __shfl_xor(gs, 2);
        sum += __shfl_xor(sum, 4); sq += __shfl_xor(sq, 4); gs += __shfl_xor(gs, 4);
        sum += __shfl_xor(sum, 8); sq += __shfl_xor(sq, 8); gs += __shfl_xor(gs, 8);
        float mu  = sum * (1.f / 128.f);
        float var = sq * (1.f / 128.f) - mu * mu;
        float ri  = rsqrtf(fmaxf(var, 0.f) + LN_EPS);
        float gate = 1.f / (1.f + expf(-(gs + gb)));
        float* orow = out + (size_t)row * H + dbase;
        #pragma unroll
        for (int t = 0; t < 8; ++t) {
            float h = fmaf((v[t] - mu) * ri, g_[t], be_[t]);
            h = fmaxf(h, 0.f);
            orow[t * 16] = fmaf(gate, h - xf[t], xf[t]);
        }
    }
}

extern "C" void kernel_launch(void* const* d_in, const int* in_sizes, int n_in,
                              void* d_out, int out_size, void* d_ws, size_t ws_size,
                              hipStream_t stream)
{
    const float* x        = (const float*)d_in[0];
    const int*   ei       = (const int*)d_in[1];
    const float* ew       = (const float*)d_in[2];
    const float* msg_w    = (const float*)d_in[3];
    const float* msg_b    = (const float*)d_in[4];
    const float* msg_g    = (const float*)d_in[5];
    const float* msg_beta = (const float*)d_in[6];
    const float* upd_w    = (const float*)d_in[7];
    const float* upd_b    = (const float*)d_in[8];
    const float* upd_g    = (const float*)d_in[9];
    const float* upd_beta = (const float*)d_in[10];
    const float* gate_w   = (const float*)d_in[11];
    const float* gate_b   = (const float*)d_in[12];

    const int n = in_sizes[0] / H;
    const int E = in_sizes[2];
    const int* src = ei;
    const int* dst = ei + E;

    char* p = (char*)d_ws;
    auto alloc = [&](size_t bytes) { char* r = p; p += (bytes + 255) & ~(size_t)255; return r; };
    int*   cnt    = (int*)alloc((size_t)n * 4);
    int*   cursor = (int*)alloc((size_t)n * 4);
    int*   srcS   = (int*)alloc((size_t)E * 4);
    float* wS     = (float*)alloc((size_t)E * 4);
    float* msgs   = (float*)alloc((size_t)n * H * 4);
    unsigned short* xb    = (unsigned short*)alloc((size_t)n * H * 2);
    unsigned short* tsrcb = (unsigned short*)alloc((size_t)n * H * 2);
    unsigned short* tdstb = (unsigned short*)alloc((size_t)n * H * 2);
    unsigned short* wtT   = (unsigned short*)alloc((size_t)H * H * 2);
    unsigned short* wbT   = (unsigned short*)alloc((size_t)H * H * 2);
    unsigned short* wuT   = (unsigned short*)alloc((size_t)2 * H * H * 2);

    hipMemsetAsync(cnt, 0, (size_t)n * 4, stream);

    int eb = (E + 255) / 256;
    count_kernel<<<eb, 256, 0, stream>>>(dst, cnt, E, n);
    scan_kernel<<<1, 1024, 0, stream>>>(cnt, cursor, n);
    bucket_kernel<<<eb, 256, 0, stream>>>(src, dst, ew, cursor, srcS, wS, E, n);

    cvt_weights<<<256, 256, 0, stream>>>(msg_w, upd_w, wtT, wbT, wuT);
    pre_both_mfma<<<(n + 63) / 64, 256, 0, stream>>>(x, wtT, wbT, msg_b, xb, tsrcb, tdstb, n);

    node_msg_kernel<<<(n + 15) / 16, 256, 0, stream>>>(tsrcb, tdstb, srcS, wS, cnt, cursor,
                                                       msg_g, msg_beta, msgs, n);

    update_mfma<<<(n + 63) / 64, 256, 0, stream>>>(x, xb, msgs, wuT, upd_b, upd_g, upd_beta,
                                                   gate_w, gate_b, (float*)d_out, n);
}

// Round 5
// 203.927 us; speedup vs baseline: 5.2775x; 1.4255x over previous
//
#include <hip/hip_runtime.h>
#include <math.h>

#define H 128
#define LN_EPS 1e-5f

typedef __attribute__((ext_vector_type(8))) short  bf16x8;
typedef __attribute__((ext_vector_type(4))) float  f32x4;
typedef __attribute__((ext_vector_type(8))) unsigned short ushort8v;

__device__ __forceinline__ int imin(int a, int b) { return a < b ? a : b; }
__device__ __forceinline__ int clampi(int v, int lo, int hi) { return v < lo ? lo : (v > hi ? hi : v); }
__device__ __forceinline__ unsigned short f2bf(float f) {
    unsigned u = __float_as_uint(f);
    unsigned r = (u + 0x7fffu + ((u >> 16) & 1u)) >> 16;   // RNE
    return (unsigned short)r;
}
__device__ __forceinline__ float bf2f(unsigned short u) {
    return __uint_as_float(((unsigned)u) << 16);
}

// ---------------- CSR build ----------------
__global__ void count_kernel(const int* __restrict__ dst, int* __restrict__ cnt, int E, int n) {
    int e = blockIdx.x * blockDim.x + threadIdx.x;
    if (e < E) {
        int d = clampi(dst[e], 0, n - 1);
        atomicAdd(&cnt[d], 1);
    }
}

// per-block exclusive scan: cursor[i] = local exclusive prefix, bsum[b] = block total
__global__ __launch_bounds__(256) void scan1_kernel(const int* __restrict__ cnt,
                                                    int* __restrict__ cursor,
                                                    int* __restrict__ bsum, int n) {
    __shared__ int wsum[4];
    const int tid = threadIdx.x, lane = tid & 63, wv = tid >> 6;
    int idx = blockIdx.x * 256 + tid;
    int v = (idx < n) ? cnt[idx] : 0;
    int s = v;
    #pragma unroll
    for (int off = 1; off < 64; off <<= 1) {
        int u = __shfl_up(s, off);
        if (lane >= off) s += u;
    }
    if (lane == 63) wsum[wv] = s;
    __syncthreads();
    int add = 0;
    for (int i = 0; i < wv; ++i) add += wsum[i];
    int incl = s + add;
    if (idx < n) cursor[idx] = incl - v;      // block-local exclusive
    if (tid == 255) bsum[blockIdx.x] = incl;  // block total
}

// single-block exclusive scan of block totals (in place), generic in nb
__global__ __launch_bounds__(256) void scan2_kernel(int* __restrict__ bsum, int nb) {
    __shared__ int wsum[4];
    const int tid = threadIdx.x, lane = tid & 63, wv = tid >> 6;
    int carry = 0;
    for (int base = 0; base < nb; base += 256) {
        int idx = base + tid;
        int v = (idx < nb) ? bsum[idx] : 0;
        int s = v;
        #pragma unroll
        for (int off = 1; off < 64; off <<= 1) {
            int u = __shfl_up(s, off);
            if (lane >= off) s += u;
        }
        if (lane == 63) wsum[wv] = s;
        __syncthreads();
        int add = 0;
        for (int i = 0; i < wv; ++i) add += wsum[i];
        if (idx < nb) bsum[idx] = s + add + carry - v;   // exclusive absolute
        int tot = wsum[0] + wsum[1] + wsum[2] + wsum[3];
        __syncthreads();
        carry += tot;
    }
}

// bucket: absolute position = local atomic cursor + block offset
__global__ void bucket_kernel(const int* __restrict__ src, const int* __restrict__ dst,
                              const float* __restrict__ ew, int* __restrict__ cursor,
                              const int* __restrict__ boff,
                              int* __restrict__ srcS, float* __restrict__ wS, int E, int n) {
    int e = blockIdx.x * blockDim.x + threadIdx.x;
    if (e < E) {
        int d = clampi(dst[e], 0, n - 1);
        int s = clampi(src[e], 0, n - 1);
        int p = atomicAdd(&cursor[d], 1) + boff[d >> 8];
        srcS[p] = s; wS[p] = ew[e];
    }
}

// ---------------- weight conversion: transpose + bf16 all four 128x128 blocks ----------------
__global__ void cvt_weights(const float* __restrict__ msg_w, const float* __restrict__ upd_w,
                            unsigned short* __restrict__ wtT, unsigned short* __restrict__ wbT,
                            unsigned short* __restrict__ wuT) {
    int tid = blockIdx.x * blockDim.x + threadIdx.x;   // 65536
    int m = tid >> 14;
    int r = tid & 16383;
    int d = r >> 7, k = r & 127;
    float v;
    unsigned short* dstp;
    if (m == 0)      { v = msg_w[k * 128 + d];          dstp = wtT; }
    else if (m == 1) { v = msg_w[(128 + k) * 128 + d];  dstp = wbT; }
    else if (m == 2) { v = upd_w[k * 128 + d];          dstp = wuT; }
    else             { v = upd_w[(128 + k) * 128 + d];  dstp = wuT + 16384; }
    dstp[d * 128 + k] = f2bf(v);
}

// ---------------- pre: tsrcb = bf16(x@Wtop), tdstb = bf16(x@Wbot + msg_b), xb = bf16(x) ----------------
__global__ __launch_bounds__(256) void pre_both_mfma(
    const float* __restrict__ x,
    const unsigned short* __restrict__ wtT, const unsigned short* __restrict__ wbT,
    const float* __restrict__ bias, unsigned short* __restrict__ xb,
    unsigned short* __restrict__ tsrcb, unsigned short* __restrict__ tdstb, int n)
{
    __shared__ unsigned short Wt[16384];
    __shared__ unsigned short Wb[16384];
    const int tid = threadIdx.x, lane = tid & 63, wv = tid >> 6;
    const int dbase = lane & 15, kgrp = lane >> 4;
    const int swzl = (dbase & 7) << 4;
    const int r0 = blockIdx.x * 64;

    {
        const ushort8v* st = (const ushort8v*)wtT;
        const ushort8v* sb = (const ushort8v*)wbT;
        for (int c = tid; c < 2048; c += 256) {
            int d = c >> 4, slot = c & 15;
            int off = d * 256 + ((slot * 16) ^ ((d & 7) << 4));
            *(ushort8v*)((char*)Wt + off) = st[c];
            *(ushort8v*)((char*)Wb + off) = sb[c];
        }
    }

    int rowA = imin(r0 + wv * 16 + dbase, n - 1);
    bf16x8 a[4];
    {
        const float* xr = x + (size_t)rowA * H + kgrp * 8;
        #pragma unroll
        for (int s = 0; s < 4; ++s) {
            float4 f0 = *(const float4*)(xr + s * 32);
            float4 f1 = *(const float4*)(xr + s * 32 + 4);
            bf16x8 v;
            v[0] = (short)f2bf(f0.x); v[1] = (short)f2bf(f0.y);
            v[2] = (short)f2bf(f0.z); v[3] = (short)f2bf(f0.w);
            v[4] = (short)f2bf(f1.x); v[5] = (short)f2bf(f1.y);
            v[6] = (short)f2bf(f1.z); v[7] = (short)f2bf(f1.w);
            a[s] = v;
            *(bf16x8*)(xb + (size_t)rowA * H + s * 32 + kgrp * 8) = v;
        }
    }
    __syncthreads();

    f32x4 accT[8], accB[8];
    #pragma unroll
    for (int t = 0; t < 8; ++t) { accT[t] = (f32x4){0.f,0.f,0.f,0.f}; accB[t] = (f32x4){0.f,0.f,0.f,0.f}; }
    #pragma unroll
    for (int s = 0; s < 4; ++s) {
        #pragma unroll
        for (int t = 0; t < 8; ++t) {
            int off = (t * 16 + dbase) * 256 + ((s * 64 + kgrp * 16) ^ swzl);
            bf16x8 bt = *(const bf16x8*)((const char*)Wt + off);
            bf16x8 bb = *(const bf16x8*)((const char*)Wb + off);
            accT[t] = __builtin_amdgcn_mfma_f32_16x16x32_bf16(a[s], bt, accT[t], 0, 0, 0);
            accB[t] = __builtin_amdgcn_mfma_f32_16x16x32_bf16(a[s], bb, accB[t], 0, 0, 0);
        }
    }

    float ub[8];
    #pragma unroll
    for (int t = 0; t < 8; ++t) ub[t] = bias[t * 16 + dbase];
    #pragma unroll
    for (int r = 0; r < 4; ++r) {
        int row = r0 + wv * 16 + kgrp * 4 + r;
        if (row < n) {
            #pragma unroll
            for (int t = 0; t < 8; ++t) {
                tsrcb[(size_t)row * H + t * 16 + dbase] = f2bf(accT[t][r]);
                tdstb[(size_t)row * H + t * 16 + dbase] = f2bf(accB[t][r] + ub[t]);
            }
        }
    }
}

// ---------------- node-centric messages: msgs[v] = mean_e relu(LN(tsrc[src_e]+tdst[v]))*w_e ----------------
__global__ __launch_bounds__(256) void node_msg_kernel(
    const unsigned short* __restrict__ tsrcb,
    const unsigned short* __restrict__ tdstb,
    const int* __restrict__ srcS, const float* __restrict__ wS,
    const int* __restrict__ cnt, const int* __restrict__ endoff,
    const int* __restrict__ boff,
    const float* __restrict__ gamma, const float* __restrict__ beta,
    float* __restrict__ msgs, int n)
{
    const int tid  = threadIdx.x;
    const int lane = tid & 63;
    const int qq   = lane & 15;               // dims qq*8 .. qq*8+7
    const int node = blockIdx.x * 16 + (tid >> 4);
    if (node >= n) return;
    const int k   = cnt[node];
    const int end = endoff[node] + boff[node >> 8];   // absolute end offset
    int e = end - k;

    float td[8];
    {
        ushort8v t = *(const ushort8v*)(tdstb + (size_t)node * H + qq * 8);
        #pragma unroll
        for (int j = 0; j < 8; ++j) td[j] = bf2f((unsigned short)t[j]);
    }
    float g_[8], b_[8];
    #pragma unroll
    for (int j = 0; j < 8; ++j) { g_[j] = gamma[qq * 8 + j]; b_[j] = beta[qq * 8 + j]; }

    float acc[8];
    #pragma unroll
    for (int j = 0; j < 8; ++j) acc[j] = 0.f;

    ushort8v a_c = {};
    float w_c = 0.f;
    if (k > 0) {
        int s = srcS[e];
        w_c = wS[e];
        a_c = *(const ushort8v*)(tsrcb + (size_t)s * H + qq * 8);
    }
    for (int i = 0; i < k; ++i) {
        ushort8v a_n = {};
        float w_n = 0.f;
        if (i + 1 < k) {                       // prefetch next edge's row
            int s = srcS[e + 1];
            w_n = wS[e + 1];
            a_n = *(const ushort8v*)(tsrcb + (size_t)s * H + qq * 8);
        }
        float v[8], sum = 0.f, sq = 0.f;
        #pragma unroll
        for (int j = 0; j < 8; ++j) {
            v[j] = td[j] + bf2f((unsigned short)a_c[j]);
            sum += v[j];
            sq = fmaf(v[j], v[j], sq);
        }
        sum += __shfl_xor(sum, 1); sq += __shfl_xor(sq, 1);
        sum += __shfl_xor(sum, 2); sq += __shfl_xor(sq, 2);
        sum += __shfl_xor(sum, 4); sq += __shfl_xor(sq, 4);
        sum += __shfl_xor(sum, 8); sq += __shfl_xor(sq, 8);
        float mu  = sum * (1.f / 128.f);
        float var = sq * (1.f / 128.f) - mu * mu;
        float ri  = rsqrtf(fmaxf(var, 0.f) + LN_EPS);
        float nmr = -mu * ri;
        #pragma unroll
        for (int j = 0; j < 8; ++j) {
            float t = fmaf(v[j], ri, nmr);
            float val = fmaf(t, g_[j], b_[j]);
            acc[j] = fmaf(fmaxf(val, 0.f), w_c, acc[j]);
        }
        a_c = a_n; w_c = w_n; ++e;
    }
    float scale = (k > 0) ? 1.f / ((float)k + 1e-8f) : 0.f;
    float* orow = msgs + (size_t)node * H + qq * 8;
    float4 o0, o1;
    o0.x = acc[0] * scale; o0.y = acc[1] * scale; o0.z = acc[2] * scale; o0.w = acc[3] * scale;
    o1.x = acc[4] * scale; o1.y = acc[5] * scale; o1.z = acc[6] * scale; o1.w = acc[7] * scale;
    *(float4*)orow = o0;
    *(float4*)(orow + 4) = o1;
}

// ---------------- update via MFMA: out = gate*relu(LN(x@Wt + m@Wb + b)) + (1-gate)*x ----------------
__global__ __launch_bounds__(256) void update_mfma(
    const float* __restrict__ x, const unsigned short* __restrict__ xb,
    const float* __restrict__ msgs,
    const unsigned short* __restrict__ wuT,   // [2][128][128] bf16 [m][d][k]
    const float* __restrict__ upd_b, const float* __restrict__ g,
    const float* __restrict__ beta, const float* __restrict__ gate_w,
    const float* __restrict__ gate_b, float* __restrict__ out, int n)
{
    __shared__ unsigned short W2[2][16384];   // 64 KB
    const int tid = threadIdx.x, lane = tid & 63, wv = tid >> 6;
    const int dbase = lane & 15, kgrp = lane >> 4;
    const int swzl = (dbase & 7) << 4;
    const int r0 = blockIdx.x * 64;

    {
        const ushort8v* srcp = (const ushort8v*)wuT;
        for (int c = tid; c < 4096; c += 256) {
            int m = c >> 11, c2 = c & 2047;
            int d = c2 >> 4, slot = c2 & 15;
            int off = m * 32768 + d * 256 + ((slot * 16) ^ ((d & 7) << 4));
            *(ushort8v*)((char*)W2 + off) = srcp[c];
        }
    }

    int rowA = imin(r0 + wv * 16 + dbase, n - 1);
    bf16x8 ax[4], am[4];
    {
        const char* arow = (const char*)(xb + (size_t)rowA * H) + kgrp * 16;
        #pragma unroll
        for (int s = 0; s < 4; ++s) ax[s] = *(const bf16x8*)(arow + s * 64);
    }
    {
        const float* mr = msgs + (size_t)rowA * H + kgrp * 8;
        #pragma unroll
        for (int s = 0; s < 4; ++s) {
            float4 f0 = *(const float4*)(mr + s * 32);
            float4 f1 = *(const float4*)(mr + s * 32 + 4);
            bf16x8 v;
            v[0] = (short)f2bf(f0.x); v[1] = (short)f2bf(f0.y);
            v[2] = (short)f2bf(f0.z); v[3] = (short)f2bf(f0.w);
            v[4] = (short)f2bf(f1.x); v[5] = (short)f2bf(f1.y);
            v[6] = (short)f2bf(f1.z); v[7] = (short)f2bf(f1.w);
            am[s] = v;
        }
    }
    __syncthreads();

    f32x4 acc[8];
    #pragma unroll
    for (int t = 0; t < 8; ++t) acc[t] = (f32x4){0.f, 0.f, 0.f, 0.f};
    #pragma unroll
    for (int s = 0; s < 4; ++s) {
        #pragma unroll
        for (int t = 0; t < 8; ++t) {
            int off = (t * 16 + dbase) * 256 + ((s * 64 + kgrp * 16) ^ swzl);
            bf16x8 b = *(const bf16x8*)((const char*)W2 + off);
            acc[t] = __builtin_amdgcn_mfma_f32_16x16x32_bf16(ax[s], b, acc[t], 0, 0, 0);
        }
    }
    #pragma unroll
    for (int s = 0; s < 4; ++s) {
        #pragma unroll
        for (int t = 0; t < 8; ++t) {
            int off = 32768 + (t * 16 + dbase) * 256 + ((s * 64 + kgrp * 16) ^ swzl);
            bf16x8 b = *(const bf16x8*)((const char*)W2 + off);
            acc[t] = __builtin_amdgcn_mfma_f32_16x16x32_bf16(am[s], b, acc[t], 0, 0, 0);
        }
    }

    float ub[8], g_[8], be_[8], gw_[8];
    #pragma unroll
    for (int t = 0; t < 8; ++t) {
        int d = t * 16 + dbase;
        ub[t] = upd_b[d]; g_[t] = g[d]; be_[t] = beta[d]; gw_[t] = gate_w[d];
    }
    const float gb = gate_b[0];

    #pragma unroll
    for (int r = 0; r < 4; ++r) {
        int row = r0 + wv * 16 + kgrp * 4 + r;
        if (row >= n) continue;
        const float* xr = x + (size_t)row * H + dbase;
        float xf[8], v[8];
        float sum = 0.f, sq = 0.f, gs = 0.f;
        #pragma unroll
        for (int t = 0; t < 8; ++t) {
            xf[t] = xr[t * 16];
            float val = acc[t][r] + ub[t];
            v[t] = val;
            sum += val;
            sq = fmaf(val, val, sq);
            gs = fmaf(xf[t], gw_[t], gs);
        }
        sum += __shfl_xor(sum, 1); sq += __shfl_xor(sq, 1); gs += __shfl_xor(gs, 1);
        sum += __shfl_xor(sum, 2); sq += __shfl_xor(sq, 2); gs += __shfl_xor(gs, 2);
        sum += __shfl_xor(sum, 4); sq += __shfl_xor(sq, 4); gs += __shfl_xor(gs, 4);
        sum += __shfl_xor(sum, 8); sq += __shfl_xor(sq, 8); gs += __shfl_xor(gs, 8);
        float mu  = sum * (1.f / 128.f);
        float var = sq * (1.f / 128.f) - mu * mu;
        float ri  = rsqrtf(fmaxf(var, 0.f) + LN_EPS);
        float gate = 1.f / (1.f + expf(-(gs + gb)));
        float* orow = out + (size_t)row * H + dbase;
        #pragma unroll
        for (int t = 0; t < 8; ++t) {
            float h = fmaf((v[t] - mu) * ri, g_[t], be_[t]);
            h = fmaxf(h, 0.f);
            orow[t * 16] = fmaf(gate, h - xf[t], xf[t]);
        }
    }
}

extern "C" void kernel_launch(void* const* d_in, const int* in_sizes, int n_in,
                              void* d_out, int out_size, void* d_ws, size_t ws_size,
                              hipStream_t stream)
{
    const float* x        = (const float*)d_in[0];
    const int*   ei       = (const int*)d_in[1];
    const float* ew       = (const float*)d_in[2];
    const float* msg_w    = (const float*)d_in[3];
    const float* msg_b    = (const float*)d_in[4];
    const float* msg_g    = (const float*)d_in[5];
    const float* msg_beta = (const float*)d_in[6];
    const float* upd_w    = (const float*)d_in[7];
    const float* upd_b    = (const float*)d_in[8];
    const float* upd_g    = (const float*)d_in[9];
    const float* upd_beta = (const float*)d_in[10];
    const float* gate_w   = (const float*)d_in[11];
    const float* gate_b   = (const float*)d_in[12];

    const int n = in_sizes[0] / H;
    const int E = in_sizes[2];
    const int* src = ei;
    const int* dst = ei + E;

    char* p = (char*)d_ws;
    auto alloc = [&](size_t bytes) { char* r = p; p += (bytes + 255) & ~(size_t)255; return r; };
    int*   cnt    = (int*)alloc((size_t)n * 4);
    int*   cursor = (int*)alloc((size_t)n * 4);
    int*   bsum   = (int*)alloc((size_t)1024 * 4);
    int*   srcS   = (int*)alloc((size_t)E * 4);
    float* wS     = (float*)alloc((size_t)E * 4);
    float* msgs   = (float*)alloc((size_t)n * H * 4);
    unsigned short* xb    = (unsigned short*)alloc((size_t)n * H * 2);
    unsigned short* tsrcb = (unsigned short*)alloc((size_t)n * H * 2);
    unsigned short* tdstb = (unsigned short*)alloc((size_t)n * H * 2);
    unsigned short* wtT   = (unsigned short*)alloc((size_t)H * H * 2);
    unsigned short* wbT   = (unsigned short*)alloc((size_t)H * H * 2);
    unsigned short* wuT   = (unsigned short*)alloc((size_t)2 * H * H * 2);

    hipMemsetAsync(cnt, 0, (size_t)n * 4, stream);

    const int nb = (n + 255) / 256;
    int eb = (E + 255) / 256;
    count_kernel<<<eb, 256, 0, stream>>>(dst, cnt, E, n);
    scan1_kernel<<<nb, 256, 0, stream>>>(cnt, cursor, bsum, n);
    scan2_kernel<<<1, 256, 0, stream>>>(bsum, nb);
    bucket_kernel<<<eb, 256, 0, stream>>>(src, dst, ew, cursor, bsum, srcS, wS, E, n);

    cvt_weights<<<256, 256, 0, stream>>>(msg_w, upd_w, wtT, wbT, wuT);
    pre_both_mfma<<<(n + 63) / 64, 256, 0, stream>>>(x, wtT, wbT, msg_b, xb, tsrcb, tdstb, n);

    node_msg_kernel<<<(n + 15) / 16, 256, 0, stream>>>(tsrcb, tdstb, srcS, wS, cnt, cursor, bsum,
                                                       msg_g, msg_beta, msgs, n);

    update_mfma<<<(n + 63) / 64, 256, 0, stream>>>(x, xb, msgs, wuT, upd_b, upd_g, upd_beta,
                                                   gate_w, gate_b, (float*)d_out, n);
}

// Round 6
// 200.238 us; speedup vs baseline: 5.3748x; 1.0184x over previous
//
#include <hip/hip_runtime.h>
#include <math.h>

#define H 128
#define LN_EPS 1e-5f

typedef __attribute__((ext_vector_type(8))) short  bf16x8;
typedef __attribute__((ext_vector_type(4))) float  f32x4;
typedef __attribute__((ext_vector_type(8))) unsigned short ushort8v;

__device__ __forceinline__ int imin(int a, int b) { return a < b ? a : b; }
__device__ __forceinline__ int clampi(int v, int lo, int hi) { return v < lo ? lo : (v > hi ? hi : v); }
__device__ __forceinline__ unsigned short f2bf(float f) {
    unsigned u = __float_as_uint(f);
    unsigned r = (u + 0x7fffu + ((u >> 16) & 1u)) >> 16;   // RNE
    return (unsigned short)r;
}
__device__ __forceinline__ float bf2f(unsigned short u) {
    return __uint_as_float(((unsigned)u) << 16);
}

// ---------------- CSR build ----------------
__global__ void count_kernel(const int* __restrict__ dst, int* __restrict__ cnt, int E, int n) {
    int e = blockIdx.x * blockDim.x + threadIdx.x;
    if (e < E) {
        int d = clampi(dst[e], 0, n - 1);
        atomicAdd(&cnt[d], 1);
    }
}

__global__ __launch_bounds__(256) void scan1_kernel(const int* __restrict__ cnt,
                                                    int* __restrict__ cursor,
                                                    int* __restrict__ bsum, int n) {
    __shared__ int wsum[4];
    const int tid = threadIdx.x, lane = tid & 63, wv = tid >> 6;
    int idx = blockIdx.x * 256 + tid;
    int v = (idx < n) ? cnt[idx] : 0;
    int s = v;
    #pragma unroll
    for (int off = 1; off < 64; off <<= 1) {
        int u = __shfl_up(s, off);
        if (lane >= off) s += u;
    }
    if (lane == 63) wsum[wv] = s;
    __syncthreads();
    int add = 0;
    for (int i = 0; i < wv; ++i) add += wsum[i];
    int incl = s + add;
    if (idx < n) cursor[idx] = incl - v;
    if (tid == 255) bsum[blockIdx.x] = incl;
}

__global__ __launch_bounds__(256) void scan2_kernel(int* __restrict__ bsum, int nb) {
    __shared__ int wsum[4];
    const int tid = threadIdx.x, lane = tid & 63, wv = tid >> 6;
    int carry = 0;
    for (int base = 0; base < nb; base += 256) {
        int idx = base + tid;
        int v = (idx < nb) ? bsum[idx] : 0;
        int s = v;
        #pragma unroll
        for (int off = 1; off < 64; off <<= 1) {
            int u = __shfl_up(s, off);
            if (lane >= off) s += u;
        }
        if (lane == 63) wsum[wv] = s;
        __syncthreads();
        int add = 0;
        for (int i = 0; i < wv; ++i) add += wsum[i];
        if (idx < nb) bsum[idx] = s + add + carry - v;
        int tot = wsum[0] + wsum[1] + wsum[2] + wsum[3];
        __syncthreads();
        carry += tot;
    }
}

__global__ void bucket_kernel(const int* __restrict__ src, const int* __restrict__ dst,
                              const float* __restrict__ ew, int* __restrict__ cursor,
                              const int* __restrict__ boff,
                              int* __restrict__ srcS, float* __restrict__ wS, int E, int n) {
    int e = blockIdx.x * blockDim.x + threadIdx.x;
    if (e < E) {
        int d = clampi(dst[e], 0, n - 1);
        int s = clampi(src[e], 0, n - 1);
        int p = atomicAdd(&cursor[d], 1) + boff[d >> 8];
        srcS[p] = s; wS[p] = ew[e];
    }
}

// ---------------- weight conversion ----------------
__global__ void cvt_weights(const float* __restrict__ msg_w, const float* __restrict__ upd_w,
                            unsigned short* __restrict__ wtT, unsigned short* __restrict__ wbT,
                            unsigned short* __restrict__ wuT) {
    int tid = blockIdx.x * blockDim.x + threadIdx.x;   // 65536
    int m = tid >> 14;
    int r = tid & 16383;
    int d = r >> 7, k = r & 127;
    float v;
    unsigned short* dstp;
    if (m == 0)      { v = msg_w[k * 128 + d];          dstp = wtT; }
    else if (m == 1) { v = msg_w[(128 + k) * 128 + d];  dstp = wbT; }
    else if (m == 2) { v = upd_w[k * 128 + d];          dstp = wuT; }
    else             { v = upd_w[(128 + k) * 128 + d];  dstp = wuT + 16384; }
    dstp[d * 128 + k] = f2bf(v);
}

// ---------------- pre: tsrcb/tdstb + per-row sums saRow/stRow + xb ----------------
__global__ __launch_bounds__(256) void pre_both_mfma(
    const float* __restrict__ x,
    const unsigned short* __restrict__ wtT, const unsigned short* __restrict__ wbT,
    const float* __restrict__ bias, unsigned short* __restrict__ xb,
    unsigned short* __restrict__ tsrcb, unsigned short* __restrict__ tdstb,
    float* __restrict__ saRow, float* __restrict__ stRow, int n)
{
    __shared__ unsigned short Wt[16384];
    __shared__ unsigned short Wb[16384];
    const int tid = threadIdx.x, lane = tid & 63, wv = tid >> 6;
    const int dbase = lane & 15, kgrp = lane >> 4;
    const int swzl = (dbase & 7) << 4;
    const int r0 = blockIdx.x * 64;

    {
        const ushort8v* st = (const ushort8v*)wtT;
        const ushort8v* sb = (const ushort8v*)wbT;
        for (int c = tid; c < 2048; c += 256) {
            int d = c >> 4, slot = c & 15;
            int off = d * 256 + ((slot * 16) ^ ((d & 7) << 4));
            *(ushort8v*)((char*)Wt + off) = st[c];
            *(ushort8v*)((char*)Wb + off) = sb[c];
        }
    }

    int rowA = imin(r0 + wv * 16 + dbase, n - 1);
    bf16x8 a[4];
    {
        const float* xr = x + (size_t)rowA * H + kgrp * 8;
        #pragma unroll
        for (int s = 0; s < 4; ++s) {
            float4 f0 = *(const float4*)(xr + s * 32);
            float4 f1 = *(const float4*)(xr + s * 32 + 4);
            bf16x8 v;
            v[0] = (short)f2bf(f0.x); v[1] = (short)f2bf(f0.y);
            v[2] = (short)f2bf(f0.z); v[3] = (short)f2bf(f0.w);
            v[4] = (short)f2bf(f1.x); v[5] = (short)f2bf(f1.y);
            v[6] = (short)f2bf(f1.z); v[7] = (short)f2bf(f1.w);
            a[s] = v;
            *(bf16x8*)(xb + (size_t)rowA * H + s * 32 + kgrp * 8) = v;
        }
    }
    __syncthreads();

    f32x4 accT[8], accB[8];
    #pragma unroll
    for (int t = 0; t < 8; ++t) { accT[t] = (f32x4){0.f,0.f,0.f,0.f}; accB[t] = (f32x4){0.f,0.f,0.f,0.f}; }
    #pragma unroll
    for (int s = 0; s < 4; ++s) {
        #pragma unroll
        for (int t = 0; t < 8; ++t) {
            int off = (t * 16 + dbase) * 256 + ((s * 64 + kgrp * 16) ^ swzl);
            bf16x8 bt = *(const bf16x8*)((const char*)Wt + off);
            bf16x8 bb = *(const bf16x8*)((const char*)Wb + off);
            accT[t] = __builtin_amdgcn_mfma_f32_16x16x32_bf16(a[s], bt, accT[t], 0, 0, 0);
            accB[t] = __builtin_amdgcn_mfma_f32_16x16x32_bf16(a[s], bb, accB[t], 0, 0, 0);
        }
    }

    float ub[8];
    #pragma unroll
    for (int t = 0; t < 8; ++t) ub[t] = bias[t * 16 + dbase];
    #pragma unroll
    for (int r = 0; r < 4; ++r) {
        int row = r0 + wv * 16 + kgrp * 4 + r;      // uniform across the 16-lane dbase group
        if (row < n) {
            unsigned short sv[8], tv[8];
            float sa = 0.f, st = 0.f;
            #pragma unroll
            for (int t = 0; t < 8; ++t) {
                unsigned short av = f2bf(accT[t][r]);
                unsigned short dv = f2bf(accB[t][r] + ub[t]);
                sv[t] = av; tv[t] = dv;
                sa += bf2f(av); st += bf2f(dv);
            }
            #pragma unroll
            for (int t = 0; t < 8; ++t) {
                tsrcb[(size_t)row * H + t * 16 + dbase] = sv[t];
                tdstb[(size_t)row * H + t * 16 + dbase] = tv[t];
            }
            sa += __shfl_xor(sa, 1); st += __shfl_xor(st, 1);
            sa += __shfl_xor(sa, 2); st += __shfl_xor(st, 2);
            sa += __shfl_xor(sa, 4); st += __shfl_xor(st, 4);
            sa += __shfl_xor(sa, 8); st += __shfl_xor(st, 8);
            if (dbase == 0) { saRow[row] = sa; stRow[row] = st; }
        }
    }
}

// ---------------- node-centric messages, bf16 out ----------------
__global__ __launch_bounds__(256) void node_msg_kernel(
    const unsigned short* __restrict__ tsrcb,
    const unsigned short* __restrict__ tdstb,
    const float* __restrict__ saRow, const float* __restrict__ stRow,
    const int* __restrict__ srcS, const float* __restrict__ wS,
    const int* __restrict__ cnt, const int* __restrict__ endoff,
    const int* __restrict__ boff,
    const float* __restrict__ gamma, const float* __restrict__ beta,
    unsigned short* __restrict__ msgsb, int n)
{
    const int tid  = threadIdx.x;
    const int lane = tid & 63;
    const int qq   = lane & 15;               // dims qq*8 .. qq*8+7
    const int node = blockIdx.x * 16 + (tid >> 4);
    if (node >= n) return;
    const int k   = cnt[node];
    const int e0  = endoff[node] + boff[node >> 8] - k;

    float td[8];
    {
        ushort8v t = *(const ushort8v*)(tdstb + (size_t)node * H + qq * 8);
        #pragma unroll
        for (int j = 0; j < 8; ++j) td[j] = bf2f((unsigned short)t[j]);
    }
    const float St = stRow[node];
    float g_[8], b_[8];
    #pragma unroll
    for (int j = 0; j < 8; ++j) { g_[j] = gamma[qq * 8 + j]; b_[j] = beta[qq * 8 + j]; }

    float acc[8];
    #pragma unroll
    for (int j = 0; j < 8; ++j) acc[j] = 0.f;

    // two edges in flight (independent LN chains)
    ushort8v A0 = {}, A1 = {};
    float W0 = 0.f, W1 = 0.f, S0 = 0.f, S1 = 0.f;
    if (k > 0) { int s = srcS[e0];     W0 = wS[e0];     S0 = saRow[s]; A0 = *(const ushort8v*)(tsrcb + (size_t)s * H + qq * 8); }
    if (k > 1) { int s = srcS[e0 + 1]; W1 = wS[e0 + 1]; S1 = saRow[s]; A1 = *(const ushort8v*)(tsrcb + (size_t)s * H + qq * 8); }

    for (int i = 0; i < k; i += 2) {
        ushort8v A2 = {}, A3 = {};
        float W2 = 0.f, W3 = 0.f, S2 = 0.f, S3 = 0.f;
        if (i + 2 < k) { int e = e0 + i + 2; int s = srcS[e]; W2 = wS[e]; S2 = saRow[s]; A2 = *(const ushort8v*)(tsrcb + (size_t)s * H + qq * 8); }
        if (i + 3 < k) { int e = e0 + i + 3; int s = srcS[e]; W3 = wS[e]; S3 = saRow[s]; A3 = *(const ushort8v*)(tsrcb + (size_t)s * H + qq * 8); }

        float v0[8], v1[8];
        float sq0 = 0.f, sq1 = 0.f;
        const bool has1 = (i + 1 < k);
        #pragma unroll
        for (int j = 0; j < 8; ++j) {
            v0[j] = td[j] + bf2f((unsigned short)A0[j]);
            sq0 = fmaf(v0[j], v0[j], sq0);
        }
        if (has1) {
            #pragma unroll
            for (int j = 0; j < 8; ++j) {
                v1[j] = td[j] + bf2f((unsigned short)A1[j]);
                sq1 = fmaf(v1[j], v1[j], sq1);
            }
        }
        sq0 += __shfl_xor(sq0, 1); sq1 += __shfl_xor(sq1, 1);
        sq0 += __shfl_xor(sq0, 2); sq1 += __shfl_xor(sq1, 2);
        sq0 += __shfl_xor(sq0, 4); sq1 += __shfl_xor(sq1, 4);
        sq0 += __shfl_xor(sq0, 8); sq1 += __shfl_xor(sq1, 8);

        {
            float mu  = (S0 + St) * (1.f / 128.f);
            float var = sq0 * (1.f / 128.f) - mu * mu;
            float ri  = rsqrtf(fmaxf(var, 0.f) + LN_EPS);
            float nmr = -mu * ri;
            #pragma unroll
            for (int j = 0; j < 8; ++j) {
                float t = fmaf(v0[j], ri, nmr);
                float val = fmaf(t, g_[j], b_[j]);
                acc[j] = fmaf(fmaxf(val, 0.f), W0, acc[j]);
            }
        }
        if (has1) {
            float mu  = (S1 + St) * (1.f / 128.f);
            float var = sq1 * (1.f / 128.f) - mu * mu;
            float ri  = rsqrtf(fmaxf(var, 0.f) + LN_EPS);
            float nmr = -mu * ri;
            #pragma unroll
            for (int j = 0; j < 8; ++j) {
                float t = fmaf(v1[j], ri, nmr);
                float val = fmaf(t, g_[j], b_[j]);
                acc[j] = fmaf(fmaxf(val, 0.f), W1, acc[j]);
            }
        }
        A0 = A2; W0 = W2; S0 = S2;
        A1 = A3; W1 = W3; S1 = S3;
    }

    float scale = (k > 0) ? 1.f / ((float)k + 1e-8f) : 0.f;
    ushort8v o;
    #pragma unroll
    for (int j = 0; j < 8; ++j) o[j] = f2bf(acc[j] * scale);
    *(ushort8v*)(msgsb + (size_t)node * H + qq * 8) = o;
}

// ---------------- update via MFMA ----------------
__global__ __launch_bounds__(256) void update_mfma(
    const unsigned short* __restrict__ xb,
    const unsigned short* __restrict__ msgsb,
    const unsigned short* __restrict__ wuT,
    const float* __restrict__ upd_b, const float* __restrict__ g,
    const float* __restrict__ beta, const float* __restrict__ gate_w,
    const float* __restrict__ gate_b, float* __restrict__ out, int n)
{
    __shared__ unsigned short W2[2][16384];   // 64 KB
    const int tid = threadIdx.x, lane = tid & 63, wv = tid >> 6;
    const int dbase = lane & 15, kgrp = lane >> 4;
    const int swzl = (dbase & 7) << 4;
    const int r0 = blockIdx.x * 64;

    {
        const ushort8v* srcp = (const ushort8v*)wuT;
        for (int c = tid; c < 4096; c += 256) {
            int m = c >> 11, c2 = c & 2047;
            int d = c2 >> 4, slot = c2 & 15;
            int off = m * 32768 + d * 256 + ((slot * 16) ^ ((d & 7) << 4));
            *(ushort8v*)((char*)W2 + off) = srcp[c];
        }
    }

    int rowA = imin(r0 + wv * 16 + dbase, n - 1);
    bf16x8 ax[4], am[4];
    {
        const char* arow = (const char*)(xb + (size_t)rowA * H) + kgrp * 16;
        const char* mrow = (const char*)(msgsb + (size_t)rowA * H) + kgrp * 16;
        #pragma unroll
        for (int s = 0; s < 4; ++s) {
            ax[s] = *(const bf16x8*)(arow + s * 64);
            am[s] = *(const bf16x8*)(mrow + s * 64);
        }
    }
    __syncthreads();

    f32x4 acc[8];
    #pragma unroll
    for (int t = 0; t < 8; ++t) acc[t] = (f32x4){0.f, 0.f, 0.f, 0.f};
    #pragma unroll
    for (int s = 0; s < 4; ++s) {
        #pragma unroll
        for (int t = 0; t < 8; ++t) {
            int off = (t * 16 + dbase) * 256 + ((s * 64 + kgrp * 16) ^ swzl);
            bf16x8 b = *(const bf16x8*)((const char*)W2 + off);
            acc[t] = __builtin_amdgcn_mfma_f32_16x16x32_bf16(ax[s], b, acc[t], 0, 0, 0);
        }
    }
    #pragma unroll
    for (int s = 0; s < 4; ++s) {
        #pragma unroll
        for (int t = 0; t < 8; ++t) {
            int off = 32768 + (t * 16 + dbase) * 256 + ((s * 64 + kgrp * 16) ^ swzl);
            bf16x8 b = *(const bf16x8*)((const char*)W2 + off);
            acc[t] = __builtin_amdgcn_mfma_f32_16x16x32_bf16(am[s], b, acc[t], 0, 0, 0);
        }
    }

    float ub[8], g_[8], be_[8], gw_[8];
    #pragma unroll
    for (int t = 0; t < 8; ++t) {
        int d = t * 16 + dbase;
        ub[t] = upd_b[d]; g_[t] = g[d]; be_[t] = beta[d]; gw_[t] = gate_w[d];
    }
    const float gb = gate_b[0];

    #pragma unroll
    for (int r = 0; r < 4; ++r) {
        int row = r0 + wv * 16 + kgrp * 4 + r;
        if (row >= n) continue;
        const unsigned short* xr = xb + (size_t)row * H + dbase;
        float xf[8], v[8];
        float sum = 0.f, sq = 0.f, gs = 0.f;
        #pragma unroll
        for (int t = 0; t < 8; ++t) {
            xf[t] = bf2f(xr[t * 16]);
            float val = acc[t][r] + ub[t];
            v[t] = val;
            sum += val;
            sq = fmaf(val, val, sq);
            gs = fmaf(xf[t], gw_[t], gs);
        }
        sum += __shfl_xor(sum, 1); sq += __shfl_xor(sq, 1); gs += __shfl_xor(gs, 1);
        sum += __shfl_xor(sum, 2); sq += __shfl_xor(sq, 2); gs += __shfl_xor(gs, 2);
        sum += __shfl_xor(sum, 4); sq += __shfl_xor(sq, 4); gs += __shfl_xor(gs, 4);
        sum += __shfl_xor(sum, 8); sq += __shfl_xor(sq, 8); gs += __shfl_xor(gs, 8);
        float mu  = sum * (1.f / 128.f);
        float var = sq * (1.f / 128.f) - mu * mu;
        float ri  = rsqrtf(fmaxf(var, 0.f) + LN_EPS);
        float gate = 1.f / (1.f + expf(-(gs + gb)));
        float* orow = out + (size_t)row * H + dbase;
        #pragma unroll
        for (int t = 0; t < 8; ++t) {
            float h = fmaf((v[t] - mu) * ri, g_[t], be_[t]);
            h = fmaxf(h, 0.f);
            orow[t * 16] = fmaf(gate, h - xf[t], xf[t]);
        }
    }
}

extern "C" void kernel_launch(void* const* d_in, const int* in_sizes, int n_in,
                              void* d_out, int out_size, void* d_ws, size_t ws_size,
                              hipStream_t stream)
{
    const float* x        = (const float*)d_in[0];
    const int*   ei       = (const int*)d_in[1];
    const float* ew       = (const float*)d_in[2];
    const float* msg_w    = (const float*)d_in[3];
    const float* msg_b    = (const float*)d_in[4];
    const float* msg_g    = (const float*)d_in[5];
    const float* msg_beta = (const float*)d_in[6];
    const float* upd_w    = (const float*)d_in[7];
    const float* upd_b    = (const float*)d_in[8];
    const float* upd_g    = (const float*)d_in[9];
    const float* upd_beta = (const float*)d_in[10];
    const float* gate_w   = (const float*)d_in[11];
    const float* gate_b   = (const float*)d_in[12];

    const int n = in_sizes[0] / H;
    const int E = in_sizes[2];
    const int* src = ei;
    const int* dst = ei + E;

    char* p = (char*)d_ws;
    auto alloc = [&](size_t bytes) { char* r = p; p += (bytes + 255) & ~(size_t)255; return r; };
    int*   cnt    = (int*)alloc((size_t)n * 4);
    int*   cursor = (int*)alloc((size_t)n * 4);
    int*   bsum   = (int*)alloc((size_t)1024 * 4);
    int*   srcS   = (int*)alloc((size_t)E * 4);
    float* wS     = (float*)alloc((size_t)E * 4);
    float* saRow  = (float*)alloc((size_t)n * 4);
    float* stRow  = (float*)alloc((size_t)n * 4);
    unsigned short* xb    = (unsigned short*)alloc((size_t)n * H * 2);
    unsigned short* tsrcb = (unsigned short*)alloc((size_t)n * H * 2);
    unsigned short* tdstb = (unsigned short*)alloc((size_t)n * H * 2);
    unsigned short* msgsb = (unsigned short*)alloc((size_t)n * H * 2);
    unsigned short* wtT   = (unsigned short*)alloc((size_t)H * H * 2);
    unsigned short* wbT   = (unsigned short*)alloc((size_t)H * H * 2);
    unsigned short* wuT   = (unsigned short*)alloc((size_t)2 * H * H * 2);

    hipMemsetAsync(cnt, 0, (size_t)n * 4, stream);

    const int nb = (n + 255) / 256;
    int eb = (E + 255) / 256;
    count_kernel<<<eb, 256, 0, stream>>>(dst, cnt, E, n);
    scan1_kernel<<<nb, 256, 0, stream>>>(cnt, cursor, bsum, n);
    scan2_kernel<<<1, 256, 0, stream>>>(bsum, nb);
    bucket_kernel<<<eb, 256, 0, stream>>>(src, dst, ew, cursor, bsum, srcS, wS, E, n);

    cvt_weights<<<256, 256, 0, stream>>>(msg_w, upd_w, wtT, wbT, wuT);
    pre_both_mfma<<<(n + 63) / 64, 256, 0, stream>>>(x, wtT, wbT, msg_b, xb, tsrcb, tdstb,
                                                     saRow, stRow, n);

    node_msg_kernel<<<(n + 15) / 16, 256, 0, stream>>>(tsrcb, tdstb, saRow, stRow, srcS, wS,
                                                       cnt, cursor, bsum, msg_g, msg_beta, msgsb, n);

    update_mfma<<<(n + 63) / 64, 256, 0, stream>>>(xb, msgsb, wuT, upd_b, upd_g, upd_beta,
                                                   gate_w, gate_b, (float*)d_out, n);
}